// Round 10
// baseline (168.633 us; speedup 1.0000x reference)
//
#include <hip/hip_runtime.h>
#include <stdint.h>

// Problem constants
#define NB 8
#define HIN 448
#define CH1 256
#define CH2 1024
#define NLOC 1024        // 32*32
#define M2 8192          // NB*NLOC
#define M1 32768         // NB*64*64 conv1 output locations
#define K1 224           // padded im2col K: c*56 + r*8 + cc(0..7), cc==7 -> 0
#define NPTS 12544
#define NOUT 4096

typedef __attribute__((ext_vector_type(8))) short bf16x8;
typedef __attribute__((ext_vector_type(4))) float f32x4;

__device__ __forceinline__ short f2bf(float f) {
  uint32_t u = __builtin_bit_cast(uint32_t, f);
  uint32_t r = (u + 0x7fffu + ((u >> 16) & 1u)) >> 16;
  return (short)r;
}
__device__ __forceinline__ float bf2f(short s) {
  return __builtin_bit_cast(float, (uint32_t)(uint16_t)s << 16);
}
__device__ __forceinline__ float gelu_f(float x) {
  return 0.5f * x * (1.0f + erff(x * 0.70710678118654752f));
}
__device__ __forceinline__ void gload_lds16(const void* g, void* l) {
  __builtin_amdgcn_global_load_lds((const __attribute__((address_space(1))) unsigned int*)g,
                                   (__attribute__((address_space(3))) unsigned int*)l, 16, 0, 0);
}

// ---- fast workspace zero ----
__global__ void k_zero(float4* __restrict__ p, int n4) {
  int i = blockIdx.x * 256 + threadIdx.x;
  if (i < n4) p[i] = make_float4(0.f, 0.f, 0.f, 0.f);
}

// ---- weight prep: cast/permute into bf16 ----
__global__ void k_wcast(const float* __restrict__ c1w, const float* __restrict__ c2w,
                        short* __restrict__ c1wb, short* __restrict__ w2p) {
  int i = blockIdx.x * 256 + threadIdx.x;
  if (i < CH1 * K1) {
    int o = i / K1, k = i - o * K1;
    int c = k / 56, kk = k - c * 56, r = kk >> 3, cc = kk & 7;
    c1wb[i] = f2bf(cc < 7 ? c1w[((o * 4 + c) * 7 + r) * 7 + cc] : 0.0f);
  }
  if (i < CH2 * CH2) {
    int o = i >> 10, k = i & 1023;
    int pos = k >> 8, ci = k & 255;
    w2p[i] = f2bf(c2w[(size_t)(o * 256 + ci) * 4 + pos]);
  }
}

// ---- point -> bilinear weight accumulation (LDS-aggregated, G12) ----
__global__ __launch_bounds__(256) void k_pts(const float* __restrict__ coords,
                                             float* __restrict__ Aw,
                                             float* __restrict__ cnt,
                                             float* __restrict__ sumAw) {
  __shared__ float lAw[NLOC];
  __shared__ int lcnt;
  __shared__ float wsum[4];
  int t = threadIdx.x;
  int b = blockIdx.x / 49;
  int blk = blockIdx.x - b * 49;
  for (int i = t; i < NLOC; i += 256) lAw[i] = 0.f;
  if (t == 0) lcnt = 0;
  __syncthreads();
  int pi = blk * 256 + t;
  float x = coords[((size_t)b * NPTS + pi) * 2];
  float y = coords[((size_t)b * NPTS + pi) * 2 + 1];
  bool valid = (x >= 0.0f);
  if (valid) {
    float gx = x * 32.0f - 0.5f, gy = y * 32.0f - 0.5f;
    float x0f = floorf(gx), y0f = floorf(gy);
    int x0 = (int)x0f, y0 = (int)y0f;
    float wx1 = gx - x0f, wx0 = 1.0f - wx1;
    float wy1 = gy - y0f, wy0 = 1.0f - wy1;
    int xs[2] = {x0, x0 + 1}, ys[2] = {y0, y0 + 1};
    float wxs[2] = {wx0, wx1}, wys[2] = {wy0, wy1};
    #pragma unroll
    for (int cy = 0; cy < 2; cy++)
      #pragma unroll
      for (int cx = 0; cx < 2; cx++) {
        int ix = xs[cx], iy = ys[cy];
        if (ix >= 0 && ix < 32 && iy >= 0 && iy < 32)
          atomicAdd(&lAw[iy * 32 + ix], wxs[cx] * wys[cy]);
      }
  }
  unsigned long long ball = __ballot(valid);
  if ((t & 63) == 0) atomicAdd(&lcnt, (int)__popcll(ball));
  __syncthreads();
  float tsum = 0.f;
  for (int i = t; i < NLOC; i += 256) {
    float v = lAw[i];
    tsum += v;
    if (v != 0.f) atomicAdd(&Aw[b * NLOC + i], v);
  }
  #pragma unroll
  for (int m = 1; m <= 32; m <<= 1) tsum += __shfl_xor(tsum, m, 64);
  if ((t & 63) == 0) wsum[t >> 6] = tsum;
  __syncthreads();
  if (t == 0) {
    float bs = wsum[0] + wsum[1] + wsum[2] + wsum[3];
    if (bs != 0.f) atomicAdd(&sumAw[b], bs);
    if (lcnt) atomicAdd(&cnt[b], (float)lcnt);
  }
}

// ---- im2col for conv1 (7x7 s7, zero duplication) ----
__global__ __launch_bounds__(256) void k_im2col(const float* __restrict__ images,
                                                const float* __restrict__ masks,
                                                short* __restrict__ A1g) {
  __shared__ float S[28 * 452];
  int t = threadIdx.x;
  int b = blockIdx.x >> 6, y = blockIdx.x & 63;
  int y7 = y * 7;
  for (int p = t; p < 3136; p += 256) {
    int row = p / 112, c4 = p - row * 112;
    int c = row / 7, r = row - c * 7;
    const float* src = (c < 3)
        ? &images[((size_t)(b * 3 + c) * 448 + y7 + r) * 448 + c4 * 4]
        : &masks[((size_t)b * 448 + y7 + r) * 448 + c4 * 4];
    *(float4*)&S[row * 452 + c4 * 4] = *(const float4*)src;
  }
  __syncthreads();
  size_t obase = (size_t)blockIdx.x * 64 * K1;
  #pragma unroll
  for (int it = 0; it < 7; it++) {
    int p = it * 256 + t;
    int x = p / 28, k16 = p - x * 28;
    const float* s = &S[k16 * 452 + x * 7];
    short o[8];
    #pragma unroll
    for (int j = 0; j < 7; j++) o[j] = f2bf(s[j]);
    o[7] = 0;
    *(bf16x8*)&A1g[obase + (size_t)p * 8] = *(bf16x8*)o;
  }
}

// ---- bf16 BT GEMM, 128x64 tile, BK=32, 2-phase dbuf; bf16 transposed store ----
// PROVEN structure (R6/R7). 64-row-tile fused variants all failed (R0/R2/R8:
// 77-94us latency-bound) -- do not refuse conv1 into its epilogue.
template<int KDIM>
__global__ __launch_bounds__(256) void k_gemm(
    const short* __restrict__ Amat, const short* __restrict__ Bmat,
    const float* __restrict__ bias, short* __restrict__ Cout, int ldc) {
  __shared__ __align__(16) char Lraw[24576];  // 2 x (A 8K + B 4K); epi ct[128][68]
  int t = threadIdx.x, lane = t & 63, wv = t >> 6;
  int mt0 = blockIdx.x * 128;
  int nt0 = blockIdx.y * 64;
  f32x4 acc[4][2];
  #pragma unroll
  for (int i = 0; i < 4; i++)
    #pragma unroll
    for (int j = 0; j < 2; j++) acc[i][j] = (f32x4){0.f, 0.f, 0.f, 0.f};

  int srow = lane >> 2, scol = (lane & 3) * 8;
  int wm = wv >> 1, wn = wv & 1;
  int l15 = lane & 15, lg = lane >> 4;
  int r0 = wv * 16, r1 = 64 + wv * 16;

  auto STAGE = [&](int buf, int kt) {
    int k0 = kt * 32;
    char* As = Lraw + buf * 12288;
    char* Bs = As + 8192;
    gload_lds16(&Amat[(size_t)(mt0 + r0 + srow) * KDIM + k0 + scol], As + r0 * 64);
    gload_lds16(&Amat[(size_t)(mt0 + r1 + srow) * KDIM + k0 + scol], As + r1 * 64);
    gload_lds16(&Bmat[(size_t)(nt0 + r0 + srow) * KDIM + k0 + scol], Bs + r0 * 64);
  };

  const int NT = KDIM / 32;
  STAGE(0, 0);
  __syncthreads();
  int cur = 0;
  #pragma unroll 2
  for (int kt = 0; kt < NT; kt++) {
    if (kt + 1 < NT) STAGE(cur ^ 1, kt + 1);
    const short* As = (const short*)(Lraw + cur * 12288);
    const short* Bs = As + 4096;
    bf16x8 af[4], bfr[2];
    #pragma unroll
    for (int i = 0; i < 4; i++)
      af[i] = *(const bf16x8*)&As[(wm * 64 + i * 16 + l15) * 32 + lg * 8];
    #pragma unroll
    for (int j = 0; j < 2; j++)
      bfr[j] = *(const bf16x8*)&Bs[(wn * 32 + j * 16 + l15) * 32 + lg * 8];
    #pragma unroll
    for (int i = 0; i < 4; i++)
      #pragma unroll
      for (int j = 0; j < 2; j++)
        acc[i][j] = __builtin_amdgcn_mfma_f32_16x16x32_bf16(af[i], bfr[j], acc[i][j], 0, 0, 0);
    __syncthreads();
    cur ^= 1;
  }

  short* ct = (short*)Lraw;
  #pragma unroll
  for (int i = 0; i < 4; i++)
    #pragma unroll
    for (int j = 0; j < 2; j++) {
      int cl = wn * 32 + j * 16 + l15;
      float bv = bias[nt0 + cl];
      #pragma unroll
      for (int reg = 0; reg < 4; reg++) {
        int rl = wm * 64 + i * 16 + lg * 4 + reg;
        ct[rl * 68 + cl] = f2bf(acc[i][j][reg] + bv);
      }
    }
  __syncthreads();
  #pragma unroll
  for (int it = 0; it < 4; it++) {
    int p = it * 256 + t;                 // 1024 16B chunks
    int row = p >> 3, cc = (p & 7) * 8;
    bf16x8 v = *(const bf16x8*)&ct[row * 68 + cc];
    *(bf16x8*)&Cout[(size_t)(mt0 + row) * ldc + nt0 + cc] = v;
  }
}

// ---- LN(256)+GELU on y1 rows, scatter to conv2-im2col layout ----
__global__ __launch_bounds__(256) void k_ln1(const short* __restrict__ y1,
                                             const float* __restrict__ ln1w,
                                             const float* __restrict__ ln1b,
                                             short* __restrict__ act1) {
  int t = threadIdx.x, wv = t >> 6, lane = t & 63;
  int c = lane * 4;
  float lw[4], lb[4];
  #pragma unroll
  for (int j = 0; j < 4; j++) { lw[j] = ln1w[c + j]; lb[j] = ln1b[c + j]; }
  int m0 = blockIdx.x * 64 + wv * 16;
  for (int r = 0; r < 16; r++) {
    int m = m0 + r;
    short4 v4 = *(const short4*)&y1[(size_t)m * 256 + c];
    float xs[4] = {bf2f(v4.x), bf2f(v4.y), bf2f(v4.z), bf2f(v4.w)};
    float s = 0.f, q = 0.f;
    #pragma unroll
    for (int j = 0; j < 4; j++) { s += xs[j]; q += xs[j] * xs[j]; }
    #pragma unroll
    for (int mm = 1; mm <= 32; mm <<= 1) { s += __shfl_xor(s, mm, 64); q += __shfl_xor(q, mm, 64); }
    float u = s * (1.0f / 256.0f);
    float rs = rsqrtf(q * (1.0f / 256.0f) - u * u + 1e-6f);
    short o[4];
    #pragma unroll
    for (int j = 0; j < 4; j++) o[j] = f2bf(gelu_f(lw[j] * ((xs[j] - u) * rs) + lb[j]));
    int b = m >> 12, y = (m >> 6) & 63, x = m & 63;
    size_t row = (size_t)(b * 32 + (y >> 1)) * 32 + (x >> 1);
    size_t addr = row * 1024 + (size_t)((y & 1) * 2 + (x & 1)) * 256 + c;
    *(short4*)&act1[addr] = make_short4(o[0], o[1], o[2], o[3]);
  }
}

// ---- fused LN(1024)+GELU+weighted-pool; early-exit on zero pool weight ----
__global__ __launch_bounds__(256) void k_ln2pool(const short* __restrict__ y2b,
                                                 const float* __restrict__ ln2w,
                                                 const float* __restrict__ ln2b,
                                                 const float* __restrict__ Aw,
                                                 float* __restrict__ pa) {
  int row = blockIdx.x, t = threadIdx.x;
  float w = Aw[row];
  if (w == 0.f) return;
  short4 v4 = *(const short4*)&y2b[(size_t)row * 1024 + t * 4];
  float xs[4] = {bf2f(v4.x), bf2f(v4.y), bf2f(v4.z), bf2f(v4.w)};
  float s = xs[0] + xs[1] + xs[2] + xs[3];
  float q = xs[0] * xs[0] + xs[1] * xs[1] + xs[2] * xs[2] + xs[3] * xs[3];
  #pragma unroll
  for (int m = 1; m <= 32; m <<= 1) { s += __shfl_xor(s, m, 64); q += __shfl_xor(q, m, 64); }
  __shared__ float ps[4], pq[4];
  int wv = t >> 6, lane = t & 63;
  if (lane == 0) { ps[wv] = s; pq[wv] = q; }
  __syncthreads();
  s = ps[0] + ps[1] + ps[2] + ps[3];
  q = pq[0] + pq[1] + pq[2] + pq[3];
  float u = s * (1.0f / 1024.0f);
  float rs = rsqrtf(q * (1.0f / 1024.0f) - u * u + 1e-6f);
  int c = t * 4;
  float* dst = &pa[(row >> 10) * 1024 + c];
  #pragma unroll
  for (int j = 0; j < 4; j++) {
    float val = gelu_f(ln2w[c + j] * ((xs[j] - u) * rs) + ln2b[c + j]);
    atomicAdd(&dst[j], w * val);
  }
}

// ---- weighted pooling over feat (f32), skipping zero-weight rows ----
__global__ __launch_bounds__(256) void k_poolf(const float* __restrict__ Aw,
                                               const float* __restrict__ feat,
                                               float* __restrict__ pf) {
  int bid = blockIdx.x;            // 256 blocks: b(8) x chunk(4) x seg(8)
  int b = bid >> 5;
  int chunk = (bid >> 3) & 3;
  int seg = bid & 7;
  int t = threadIdx.x;
  int ch = chunk * 256 + t;
  const float* aw = Aw + b * NLOC + seg * 128;
  const float* xp = feat + ((size_t)(b * NLOC + seg * 128)) * 1024 + ch;
  float acc = 0.f;
  for (int i = 0; i < 128; i++) {
    float a = aw[i];
    if (a != 0.f) acc += a * xp[(size_t)i * 1024];
  }
  atomicAdd(&pf[b * NLOC + ch], acc);
}

// ---- conv3 folded past the pool ----
__global__ __launch_bounds__(256) void k_mix(const float* __restrict__ pa,
                                             const float* __restrict__ pf,
                                             const float* __restrict__ sumAw,
                                             const float* __restrict__ cnt,
                                             const float* __restrict__ c3w,
                                             const float* __restrict__ c3b,
                                             float* __restrict__ zn) {
  int t = threadIdx.x, wv = t >> 6, lane = t & 63;
  int idx = blockIdx.x * 4 + wv;   // 0..8191 = b*1024 + c
  int b = idx >> 10, c = idx & 1023;
  float s = 0.f;
  #pragma unroll
  for (int i = 0; i < 16; i++) {
    int k = i * 64 + lane;
    s += c3w[(size_t)c * 1024 + k] * pa[b * 1024 + k];
  }
  #pragma unroll
  for (int m = 1; m <= 32; m <<= 1) s += __shfl_xor(s, m, 64);
  if (lane == 0) {
    float z = s + sumAw[b] * c3b[c] + pf[idx];
    float cv = cnt[b];
    zn[idx] = cv > 0.f ? z / cv : 0.f;   // nan_to_num
  }
}

// ---- final GEMV: 1024 blocks, one wave per output row, 8 batches/wave ----
__global__ __launch_bounds__(256) void k_out(const float* __restrict__ zn,
                                             const float* __restrict__ up_w,
                                             const float* __restrict__ up_b,
                                             float* __restrict__ out) {
  __shared__ float pl[8192];
  int t = threadIdx.x;
  for (int idx = t; idx < 2048; idx += 256)
    ((float4*)pl)[idx] = ((const float4*)zn)[idx];
  __syncthreads();
  int wv = t >> 6, lane = t & 63;
  int o = blockIdx.x * 4 + wv;
  float w[16];
  #pragma unroll
  for (int i = 0; i < 16; i++) w[i] = up_w[(size_t)o * 1024 + i * 64 + lane];
  float s[8];
  #pragma unroll
  for (int b = 0; b < 8; b++) s[b] = 0.f;
  #pragma unroll
  for (int i = 0; i < 16; i++) {
    int k = i * 64 + lane;
    #pragma unroll
    for (int b = 0; b < 8; b++) s[b] += w[i] * pl[b * 1024 + k];
  }
  #pragma unroll
  for (int m = 1; m <= 32; m <<= 1)
    #pragma unroll
    for (int b = 0; b < 8; b++) s[b] += __shfl_xor(s[b], m, 64);
  if (lane < 8) out[(size_t)lane * NOUT + o] = s[lane] + up_b[o];
}

extern "C" void kernel_launch(void* const* d_in, const int* in_sizes, int n_in,
                              void* d_out, int out_size, void* d_ws, size_t ws_size,
                              hipStream_t stream) {
  const float* images = (const float*)d_in[0];
  const float* masks  = (const float*)d_in[1];
  const float* feat   = (const float*)d_in[2];   // [B,1024(loc),1024(emb)]
  const float* coords = (const float*)d_in[3];
  const float* c1w  = (const float*)d_in[5];
  const float* c1b  = (const float*)d_in[6];
  const float* ln1w = (const float*)d_in[7];
  const float* ln1b = (const float*)d_in[8];
  const float* c2w  = (const float*)d_in[9];
  const float* c2b  = (const float*)d_in[10];
  const float* ln2w = (const float*)d_in[11];
  const float* ln2b = (const float*)d_in[12];
  const float* c3w  = (const float*)d_in[13];
  const float* c3b  = (const float*)d_in[14];
  const float* up_w = (const float*)d_in[15];
  const float* up_b = (const float*)d_in[16];
  float* out = (float*)d_out;

  char* ws = (char*)d_ws;
  size_t off = 0;
  auto alloc = [&](size_t bytes) -> void* {
    void* p = ws + off;
    off = (off + bytes + 255) & ~(size_t)255;
    return p;
  };
  float* Aw    = (float*)alloc(8192 * 4);
  float* cnt   = (float*)alloc(8 * 4);
  float* sumAw = (float*)alloc(8 * 4);
  float* pa    = (float*)alloc(8192 * 4);   // pooled act2 (atomics from k_ln2pool)
  float* pf    = (float*)alloc(8192 * 4);   // pooled feat
  size_t zeroBytes = off;
  float* zn   = (float*)alloc(8192 * 4);
  short* c1wb = (short*)alloc((size_t)CH1 * K1 * 2);
  short* w2p  = (short*)alloc((size_t)CH2 * CH2 * 2);
  short* act1 = (short*)alloc((size_t)M2 * 1024 * 2);
  short* slotB = (short*)alloc((size_t)M2 * 1024 * 2);  // A1g then y2b
  short* y1   = (short*)alloc((size_t)M1 * 256 * 2);    // conv1 pre-LN out
  short* A1g  = slotB;   // im2col, dead before conv2 writes y2b
  short* y2b  = slotB;

  int n4 = (int)(zeroBytes / 16);
  k_zero<<<(n4 + 255) / 256, 256, 0, stream>>>((float4*)d_ws, n4);
  k_wcast<<<4096, 256, 0, stream>>>(c1w, c2w, c1wb, w2p);
  k_pts<<<NB * 49, 256, 0, stream>>>(coords, Aw, cnt, sumAw);
  k_im2col<<<512, 256, 0, stream>>>(images, masks, A1g);
  k_gemm<K1><<<dim3(M1 / 128, 4), 256, 0, stream>>>(A1g, c1wb, c1b, y1, 256);
  k_ln1<<<M1 / 64, 256, 0, stream>>>(y1, ln1w, ln1b, act1);
  k_gemm<1024><<<dim3(M2 / 128, 16), 256, 0, stream>>>(act1, w2p, c2b, y2b, 1024);
  k_ln2pool<<<M2, 256, 0, stream>>>(y2b, ln2w, ln2b, Aw, pa);
  k_poolf<<<256, 256, 0, stream>>>(Aw, feat, pf);
  k_mix<<<2048, 256, 0, stream>>>(pa, pf, sumAw, cnt, c3w, c3b, zn);
  k_out<<<NOUT / 4, 256, 0, stream>>>(zn, up_w, up_b, out);
}

// Round 11
// 150.511 us; speedup vs baseline: 1.1204x; 1.1204x over previous
//
#include <hip/hip_runtime.h>
#include <stdint.h>

// Problem constants
#define NB 8
#define HIN 448
#define CH1 256
#define CH2 1024
#define NLOC 1024        // 32*32
#define M2 8192          // NB*NLOC
#define M1 32768         // NB*64*64 conv1 output locations
#define K1 224           // padded im2col K: c*56 + r*8 + cc(0..7), cc==7 -> 0
#define NPTS 12544
#define NOUT 4096

typedef __attribute__((ext_vector_type(8))) short bf16x8;
typedef __attribute__((ext_vector_type(4))) float f32x4;

__device__ __forceinline__ short f2bf(float f) {
  uint32_t u = __builtin_bit_cast(uint32_t, f);
  uint32_t r = (u + 0x7fffu + ((u >> 16) & 1u)) >> 16;
  return (short)r;
}
__device__ __forceinline__ float bf2f(short s) {
  return __builtin_bit_cast(float, (uint32_t)(uint16_t)s << 16);
}
__device__ __forceinline__ float gelu_f(float x) {
  return 0.5f * x * (1.0f + erff(x * 0.70710678118654752f));
}
__device__ __forceinline__ void gload_lds16(const void* g, void* l) {
  __builtin_amdgcn_global_load_lds((const __attribute__((address_space(1))) unsigned int*)g,
                                   (__attribute__((address_space(3))) unsigned int*)l, 16, 0, 0);
}

// ---- fast workspace zero ----
__global__ void k_zero(float4* __restrict__ p, int n4) {
  int i = blockIdx.x * 256 + threadIdx.x;
  if (i < n4) p[i] = make_float4(0.f, 0.f, 0.f, 0.f);
}

// ---- weight prep: cast/permute into bf16 ----
__global__ void k_wcast(const float* __restrict__ c1w, const float* __restrict__ c2w,
                        short* __restrict__ c1wb, short* __restrict__ w2p) {
  int i = blockIdx.x * 256 + threadIdx.x;
  if (i < CH1 * K1) {
    int o = i / K1, k = i - o * K1;
    int c = k / 56, kk = k - c * 56, r = kk >> 3, cc = kk & 7;
    c1wb[i] = f2bf(cc < 7 ? c1w[((o * 4 + c) * 7 + r) * 7 + cc] : 0.0f);
  }
  if (i < CH2 * CH2) {
    int o = i >> 10, k = i & 1023;
    int pos = k >> 8, ci = k & 255;
    w2p[i] = f2bf(c2w[(size_t)(o * 256 + ci) * 4 + pos]);
  }
}

// ---- point -> bilinear weight accumulation (LDS-aggregated, G12) ----
__global__ __launch_bounds__(256) void k_pts(const float* __restrict__ coords,
                                             float* __restrict__ Aw,
                                             float* __restrict__ cnt,
                                             float* __restrict__ sumAw) {
  __shared__ float lAw[NLOC];
  __shared__ int lcnt;
  __shared__ float wsum[4];
  int t = threadIdx.x;
  int b = blockIdx.x / 49;
  int blk = blockIdx.x - b * 49;
  for (int i = t; i < NLOC; i += 256) lAw[i] = 0.f;
  if (t == 0) lcnt = 0;
  __syncthreads();
  int pi = blk * 256 + t;
  float x = coords[((size_t)b * NPTS + pi) * 2];
  float y = coords[((size_t)b * NPTS + pi) * 2 + 1];
  bool valid = (x >= 0.0f);
  if (valid) {
    float gx = x * 32.0f - 0.5f, gy = y * 32.0f - 0.5f;
    float x0f = floorf(gx), y0f = floorf(gy);
    int x0 = (int)x0f, y0 = (int)y0f;
    float wx1 = gx - x0f, wx0 = 1.0f - wx1;
    float wy1 = gy - y0f, wy0 = 1.0f - wy1;
    int xs[2] = {x0, x0 + 1}, ys[2] = {y0, y0 + 1};
    float wxs[2] = {wx0, wx1}, wys[2] = {wy0, wy1};
    #pragma unroll
    for (int cy = 0; cy < 2; cy++)
      #pragma unroll
      for (int cx = 0; cx < 2; cx++) {
        int ix = xs[cx], iy = ys[cy];
        if (ix >= 0 && ix < 32 && iy >= 0 && iy < 32)
          atomicAdd(&lAw[iy * 32 + ix], wxs[cx] * wys[cy]);
      }
  }
  unsigned long long ball = __ballot(valid);
  if ((t & 63) == 0) atomicAdd(&lcnt, (int)__popcll(ball));
  __syncthreads();
  float tsum = 0.f;
  for (int i = t; i < NLOC; i += 256) {
    float v = lAw[i];
    tsum += v;
    if (v != 0.f) atomicAdd(&Aw[b * NLOC + i], v);
  }
  #pragma unroll
  for (int m = 1; m <= 32; m <<= 1) tsum += __shfl_xor(tsum, m, 64);
  if ((t & 63) == 0) wsum[t >> 6] = tsum;
  __syncthreads();
  if (t == 0) {
    float bs = wsum[0] + wsum[1] + wsum[2] + wsum[3];
    if (bs != 0.f) atomicAdd(&sumAw[b], bs);
    if (lcnt) atomicAdd(&cnt[b], (float)lcnt);
  }
}

// ---- im2col for conv1 (7x7 s7, zero duplication) ----
__global__ __launch_bounds__(256) void k_im2col(const float* __restrict__ images,
                                                const float* __restrict__ masks,
                                                short* __restrict__ A1g) {
  __shared__ float S[28 * 452];
  int t = threadIdx.x;
  int b = blockIdx.x >> 6, y = blockIdx.x & 63;
  int y7 = y * 7;
  for (int p = t; p < 3136; p += 256) {
    int row = p / 112, c4 = p - row * 112;
    int c = row / 7, r = row - c * 7;
    const float* src = (c < 3)
        ? &images[((size_t)(b * 3 + c) * 448 + y7 + r) * 448 + c4 * 4]
        : &masks[((size_t)b * 448 + y7 + r) * 448 + c4 * 4];
    *(float4*)&S[row * 452 + c4 * 4] = *(const float4*)src;
  }
  __syncthreads();
  size_t obase = (size_t)blockIdx.x * 64 * K1;
  #pragma unroll
  for (int it = 0; it < 7; it++) {
    int p = it * 256 + t;
    int x = p / 28, k16 = p - x * 28;
    const float* s = &S[k16 * 452 + x * 7];
    short o[8];
    #pragma unroll
    for (int j = 0; j < 7; j++) o[j] = f2bf(s[j]);
    o[7] = 0;
    *(bf16x8*)&A1g[obase + (size_t)p * 8] = *(bf16x8*)o;
  }
}

// ---- bf16 BT GEMM, 128x64 tile, BK=32, 2-phase dbuf; bf16 transposed store ----
// PROVEN structure (R6/R7). 64-row-tile fused variants all failed (R0/R2/R8:
// 77-94us latency-bound) -- do not fuse conv1 into a 64-row epilogue.
template<int KDIM>
__global__ __launch_bounds__(256) void k_gemm(
    const short* __restrict__ Amat, const short* __restrict__ Bmat,
    const float* __restrict__ bias, short* __restrict__ Cout, int ldc) {
  __shared__ __align__(16) char Lraw[24576];  // 2 x (A 8K + B 4K); epi ct[128][68]
  int t = threadIdx.x, lane = t & 63, wv = t >> 6;
  int mt0 = blockIdx.x * 128;
  int nt0 = blockIdx.y * 64;
  f32x4 acc[4][2];
  #pragma unroll
  for (int i = 0; i < 4; i++)
    #pragma unroll
    for (int j = 0; j < 2; j++) acc[i][j] = (f32x4){0.f, 0.f, 0.f, 0.f};

  int srow = lane >> 2, scol = (lane & 3) * 8;
  int wm = wv >> 1, wn = wv & 1;
  int l15 = lane & 15, lg = lane >> 4;
  int r0 = wv * 16, r1 = 64 + wv * 16;

  auto STAGE = [&](int buf, int kt) {
    int k0 = kt * 32;
    char* As = Lraw + buf * 12288;
    char* Bs = As + 8192;
    gload_lds16(&Amat[(size_t)(mt0 + r0 + srow) * KDIM + k0 + scol], As + r0 * 64);
    gload_lds16(&Amat[(size_t)(mt0 + r1 + srow) * KDIM + k0 + scol], As + r1 * 64);
    gload_lds16(&Bmat[(size_t)(nt0 + r0 + srow) * KDIM + k0 + scol], Bs + r0 * 64);
  };

  const int NT = KDIM / 32;
  STAGE(0, 0);
  __syncthreads();
  int cur = 0;
  #pragma unroll 2
  for (int kt = 0; kt < NT; kt++) {
    if (kt + 1 < NT) STAGE(cur ^ 1, kt + 1);
    const short* As = (const short*)(Lraw + cur * 12288);
    const short* Bs = As + 4096;
    bf16x8 af[4], bfr[2];
    #pragma unroll
    for (int i = 0; i < 4; i++)
      af[i] = *(const bf16x8*)&As[(wm * 64 + i * 16 + l15) * 32 + lg * 8];
    #pragma unroll
    for (int j = 0; j < 2; j++)
      bfr[j] = *(const bf16x8*)&Bs[(wn * 32 + j * 16 + l15) * 32 + lg * 8];
    #pragma unroll
    for (int i = 0; i < 4; i++)
      #pragma unroll
      for (int j = 0; j < 2; j++)
        acc[i][j] = __builtin_amdgcn_mfma_f32_16x16x32_bf16(af[i], bfr[j], acc[i][j], 0, 0, 0);
    __syncthreads();
    cur ^= 1;
  }

  short* ct = (short*)Lraw;
  #pragma unroll
  for (int i = 0; i < 4; i++)
    #pragma unroll
    for (int j = 0; j < 2; j++) {
      int cl = wn * 32 + j * 16 + l15;
      float bv = bias[nt0 + cl];
      #pragma unroll
      for (int reg = 0; reg < 4; reg++) {
        int rl = wm * 64 + i * 16 + lg * 4 + reg;
        ct[rl * 68 + cl] = f2bf(acc[i][j][reg] + bv);
      }
    }
  __syncthreads();
  #pragma unroll
  for (int it = 0; it < 4; it++) {
    int p = it * 256 + t;                 // 1024 16B chunks
    int row = p >> 3, cc = (p & 7) * 8;
    bf16x8 v = *(const bf16x8*)&ct[row * 68 + cc];
    *(bf16x8*)&Cout[(size_t)(mt0 + row) * ldc + nt0 + cc] = v;
  }
}

// ---- LN(256)+GELU on y1 rows, scatter to conv2-im2col layout ----
__global__ __launch_bounds__(256) void k_ln1(const short* __restrict__ y1,
                                             const float* __restrict__ ln1w,
                                             const float* __restrict__ ln1b,
                                             short* __restrict__ act1) {
  int t = threadIdx.x, wv = t >> 6, lane = t & 63;
  int c = lane * 4;
  float lw[4], lb[4];
  #pragma unroll
  for (int j = 0; j < 4; j++) { lw[j] = ln1w[c + j]; lb[j] = ln1b[c + j]; }
  int m0 = blockIdx.x * 64 + wv * 16;
  for (int r = 0; r < 16; r++) {
    int m = m0 + r;
    short4 v4 = *(const short4*)&y1[(size_t)m * 256 + c];
    float xs[4] = {bf2f(v4.x), bf2f(v4.y), bf2f(v4.z), bf2f(v4.w)};
    float s = 0.f, q = 0.f;
    #pragma unroll
    for (int j = 0; j < 4; j++) { s += xs[j]; q += xs[j] * xs[j]; }
    #pragma unroll
    for (int mm = 1; mm <= 32; mm <<= 1) { s += __shfl_xor(s, mm, 64); q += __shfl_xor(q, mm, 64); }
    float u = s * (1.0f / 256.0f);
    float rs = rsqrtf(q * (1.0f / 256.0f) - u * u + 1e-6f);
    short o[4];
    #pragma unroll
    for (int j = 0; j < 4; j++) o[j] = f2bf(gelu_f(lw[j] * ((xs[j] - u) * rs) + lb[j]));
    int b = m >> 12, y = (m >> 6) & 63, x = m & 63;
    size_t row = (size_t)(b * 32 + (y >> 1)) * 32 + (x >> 1);
    size_t addr = row * 1024 + (size_t)((y & 1) * 2 + (x & 1)) * 256 + c;
    *(short4*)&act1[addr] = make_short4(o[0], o[1], o[2], o[3]);
  }
}

// ---- fused LN(1024)+GELU+weighted-pool, ATOMIC-FREE (G12: reduce locally) ----
// 256 blocks = 8 batches x 32 row-chunks; one WAVE per row (wave-local LN
// reduce, no barriers); lane owns 16 channels; partial sums in registers,
// written once. k_red then sums 128 partials per (b,c).
__global__ __launch_bounds__(256) void k_ln2poolp(const short* __restrict__ y2b,
                                                  const float* __restrict__ ln2w,
                                                  const float* __restrict__ ln2b,
                                                  const float* __restrict__ Aw,
                                                  float* __restrict__ partials) {
  int t = threadIdx.x, wv = t >> 6, lane = t & 63;
  int b = blockIdx.x >> 5, chunk = blockIdx.x & 31;
  int base = b * 1024 + chunk * 32;
  int c0 = lane * 16;
  float lw[16], lb[16], wacc[16];
  #pragma unroll
  for (int j = 0; j < 16; j++) {
    lw[j] = ln2w[c0 + j];
    lb[j] = ln2b[c0 + j];
    wacc[j] = 0.f;
  }
  for (int pass = 0; pass < 8; pass++) {
    int row = base + pass * 4 + wv;
    float wt = Aw[row];
    if (wt == 0.f) continue;            // wave-uniform skip (~75-90% of rows)
    bf16x8 v0 = *(const bf16x8*)&y2b[(size_t)row * 1024 + c0];
    bf16x8 v1 = *(const bf16x8*)&y2b[(size_t)row * 1024 + c0 + 8];
    float xs[16];
    #pragma unroll
    for (int j = 0; j < 8; j++) { xs[j] = bf2f(v0[j]); xs[8 + j] = bf2f(v1[j]); }
    float s = 0.f, q = 0.f;
    #pragma unroll
    for (int j = 0; j < 16; j++) { s += xs[j]; q += xs[j] * xs[j]; }
    #pragma unroll
    for (int m = 1; m <= 32; m <<= 1) { s += __shfl_xor(s, m, 64); q += __shfl_xor(q, m, 64); }
    float u = s * (1.0f / 1024.0f);
    float rs = rsqrtf(q * (1.0f / 1024.0f) - u * u + 1e-6f);
    #pragma unroll
    for (int j = 0; j < 16; j++)
      wacc[j] += wt * gelu_f(lw[j] * ((xs[j] - u) * rs) + lb[j]);
  }
  float* dst = &partials[((size_t)blockIdx.x * 4 + wv) * 1024 + c0];
  #pragma unroll
  for (int j = 0; j < 4; j++)
    *(f32x4*)&dst[j * 4] = (f32x4){wacc[j * 4], wacc[j * 4 + 1], wacc[j * 4 + 2], wacc[j * 4 + 3]};
}

// ---- reduce partials: pa[b][c] = sum_{j<128} partials[b*128+j][c] ----
__global__ __launch_bounds__(256) void k_red(const float* __restrict__ partials,
                                             float* __restrict__ pa) {
  int c = blockIdx.x * 256 + threadIdx.x;   // 0..8191
  int b = c >> 10, ch = c & 1023;
  const float* p = partials + (size_t)(b * 128) * 1024 + ch;
  float s = 0.f;
  #pragma unroll 8
  for (int j = 0; j < 128; j++) s += p[(size_t)j * 1024];
  pa[c] = s;
}

// ---- weighted pooling over feat (f32), skipping zero-weight rows ----
__global__ __launch_bounds__(256) void k_poolf(const float* __restrict__ Aw,
                                               const float* __restrict__ feat,
                                               float* __restrict__ pf) {
  int bid = blockIdx.x;            // 256 blocks: b(8) x chunk(4) x seg(8)
  int b = bid >> 5;
  int chunk = (bid >> 3) & 3;
  int seg = bid & 7;
  int t = threadIdx.x;
  int ch = chunk * 256 + t;
  const float* aw = Aw + b * NLOC + seg * 128;
  const float* xp = feat + ((size_t)(b * NLOC + seg * 128)) * 1024 + ch;
  float acc = 0.f;
  for (int i = 0; i < 128; i++) {
    float a = aw[i];
    if (a != 0.f) acc += a * xp[(size_t)i * 1024];
  }
  atomicAdd(&pf[b * NLOC + ch], acc);
}

// ---- conv3 folded past the pool ----
__global__ __launch_bounds__(256) void k_mix(const float* __restrict__ pa,
                                             const float* __restrict__ pf,
                                             const float* __restrict__ sumAw,
                                             const float* __restrict__ cnt,
                                             const float* __restrict__ c3w,
                                             const float* __restrict__ c3b,
                                             float* __restrict__ zn) {
  int t = threadIdx.x, wv = t >> 6, lane = t & 63;
  int idx = blockIdx.x * 4 + wv;   // 0..8191 = b*1024 + c
  int b = idx >> 10, c = idx & 1023;
  float s = 0.f;
  #pragma unroll
  for (int i = 0; i < 16; i++) {
    int k = i * 64 + lane;
    s += c3w[(size_t)c * 1024 + k] * pa[b * 1024 + k];
  }
  #pragma unroll
  for (int m = 1; m <= 32; m <<= 1) s += __shfl_xor(s, m, 64);
  if (lane == 0) {
    float z = s + sumAw[b] * c3b[c] + pf[idx];
    float cv = cnt[b];
    zn[idx] = cv > 0.f ? z / cv : 0.f;   // nan_to_num
  }
}

// ---- final GEMV: 1024 blocks, one wave per output row, 8 batches/wave ----
__global__ __launch_bounds__(256) void k_out(const float* __restrict__ zn,
                                             const float* __restrict__ up_w,
                                             const float* __restrict__ up_b,
                                             float* __restrict__ out) {
  __shared__ float pl[8192];
  int t = threadIdx.x;
  for (int idx = t; idx < 2048; idx += 256)
    ((float4*)pl)[idx] = ((const float4*)zn)[idx];
  __syncthreads();
  int wv = t >> 6, lane = t & 63;
  int o = blockIdx.x * 4 + wv;
  float w[16];
  #pragma unroll
  for (int i = 0; i < 16; i++) w[i] = up_w[(size_t)o * 1024 + i * 64 + lane];
  float s[8];
  #pragma unroll
  for (int b = 0; b < 8; b++) s[b] = 0.f;
  #pragma unroll
  for (int i = 0; i < 16; i++) {
    int k = i * 64 + lane;
    #pragma unroll
    for (int b = 0; b < 8; b++) s[b] += w[i] * pl[b * 1024 + k];
  }
  #pragma unroll
  for (int m = 1; m <= 32; m <<= 1)
    #pragma unroll
    for (int b = 0; b < 8; b++) s[b] += __shfl_xor(s[b], m, 64);
  if (lane < 8) out[(size_t)lane * NOUT + o] = s[lane] + up_b[o];
}

extern "C" void kernel_launch(void* const* d_in, const int* in_sizes, int n_in,
                              void* d_out, int out_size, void* d_ws, size_t ws_size,
                              hipStream_t stream) {
  const float* images = (const float*)d_in[0];
  const float* masks  = (const float*)d_in[1];
  const float* feat   = (const float*)d_in[2];   // [B,1024(loc),1024(emb)]
  const float* coords = (const float*)d_in[3];
  const float* c1w  = (const float*)d_in[5];
  const float* c1b  = (const float*)d_in[6];
  const float* ln1w = (const float*)d_in[7];
  const float* ln1b = (const float*)d_in[8];
  const float* c2w  = (const float*)d_in[9];
  const float* c2b  = (const float*)d_in[10];
  const float* ln2w = (const float*)d_in[11];
  const float* ln2b = (const float*)d_in[12];
  const float* c3w  = (const float*)d_in[13];
  const float* c3b  = (const float*)d_in[14];
  const float* up_w = (const float*)d_in[15];
  const float* up_b = (const float*)d_in[16];
  float* out = (float*)d_out;

  char* ws = (char*)d_ws;
  size_t off = 0;
  auto alloc = [&](size_t bytes) -> void* {
    void* p = ws + off;
    off = (off + bytes + 255) & ~(size_t)255;
    return p;
  };
  float* Aw    = (float*)alloc(8192 * 4);
  float* cnt   = (float*)alloc(8 * 4);
  float* sumAw = (float*)alloc(8 * 4);
  float* pf    = (float*)alloc(8192 * 4);   // pooled feat (atomics, 65K total)
  size_t zeroBytes = off;
  float* pa       = (float*)alloc(8192 * 4);              // pooled act2 (from k_red)
  float* partials = (float*)alloc((size_t)1024 * 1024 * 4);  // [256*4][1024]
  float* zn   = (float*)alloc(8192 * 4);
  short* c1wb = (short*)alloc((size_t)CH1 * K1 * 2);
  short* w2p  = (short*)alloc((size_t)CH2 * CH2 * 2);
  short* act1 = (short*)alloc((size_t)M2 * 1024 * 2);
  short* slotB = (short*)alloc((size_t)M2 * 1024 * 2);  // A1g then y2b
  short* y1   = (short*)alloc((size_t)M1 * 256 * 2);    // conv1 pre-LN out
  short* A1g  = slotB;   // im2col, dead before conv2 writes y2b
  short* y2b  = slotB;

  int n4 = (int)(zeroBytes / 16);
  k_zero<<<(n4 + 255) / 256, 256, 0, stream>>>((float4*)d_ws, n4);
  k_wcast<<<4096, 256, 0, stream>>>(c1w, c2w, c1wb, w2p);
  k_pts<<<NB * 49, 256, 0, stream>>>(coords, Aw, cnt, sumAw);
  k_im2col<<<512, 256, 0, stream>>>(images, masks, A1g);
  k_gemm<K1><<<dim3(M1 / 128, 4), 256, 0, stream>>>(A1g, c1wb, c1b, y1, 256);
  k_ln1<<<M1 / 64, 256, 0, stream>>>(y1, ln1w, ln1b, act1);
  k_gemm<1024><<<dim3(M2 / 128, 16), 256, 0, stream>>>(act1, w2p, c2b, y2b, 1024);
  k_ln2poolp<<<256, 256, 0, stream>>>(y2b, ln2w, ln2b, Aw, partials);
  k_red<<<32, 256, 0, stream>>>(partials, pa);
  k_poolf<<<256, 256, 0, stream>>>(Aw, feat, pf);
  k_mix<<<2048, 256, 0, stream>>>(pa, pf, sumAw, cnt, c3w, c3b, zn);
  k_out<<<NOUT / 4, 256, 0, stream>>>(zn, up_w, up_b, out);
}

// Round 12
// 141.286 us; speedup vs baseline: 1.1936x; 1.0653x over previous
//
#include <hip/hip_runtime.h>
#include <stdint.h>

// Problem constants
#define NB 8
#define HIN 448
#define CH1 256
#define CH2 1024
#define NLOC 1024        // 32*32
#define M2 8192          // NB*NLOC
#define M1 32768         // NB*64*64 conv1 output locations
#define K1 224           // padded im2col K: c*56 + r*8 + cc(0..7), cc==7 -> 0
#define NPTS 12544
#define NOUT 4096
#define CAP 384          // per-batch compacted-row capacity (>= 18*18=324 bound)
#define MC (NB * CAP)    // 3072 compacted conv2 rows

typedef __attribute__((ext_vector_type(8))) short bf16x8;
typedef __attribute__((ext_vector_type(4))) float f32x4;

__device__ __forceinline__ short f2bf(float f) {
  uint32_t u = __builtin_bit_cast(uint32_t, f);
  uint32_t r = (u + 0x7fffu + ((u >> 16) & 1u)) >> 16;
  return (short)r;
}
__device__ __forceinline__ float bf2f(short s) {
  return __builtin_bit_cast(float, (uint32_t)(uint16_t)s << 16);
}
__device__ __forceinline__ float gelu_f(float x) {
  return 0.5f * x * (1.0f + erff(x * 0.70710678118654752f));
}
__device__ __forceinline__ void gload_lds16(const void* g, void* l) {
  __builtin_amdgcn_global_load_lds((const __attribute__((address_space(1))) unsigned int*)g,
                                   (__attribute__((address_space(3))) unsigned int*)l, 16, 0, 0);
}

// ---- fast workspace zero ----
__global__ void k_zero(float4* __restrict__ p, int n4) {
  int i = blockIdx.x * 256 + threadIdx.x;
  if (i < n4) p[i] = make_float4(0.f, 0.f, 0.f, 0.f);
}

// ---- weight prep: cast/permute into bf16 ----
__global__ void k_wcast(const float* __restrict__ c1w, const float* __restrict__ c2w,
                        short* __restrict__ c1wb, short* __restrict__ w2p) {
  int i = blockIdx.x * 256 + threadIdx.x;
  if (i < CH1 * K1) {
    int o = i / K1, k = i - o * K1;
    int c = k / 56, kk = k - c * 56, r = kk >> 3, cc = kk & 7;
    c1wb[i] = f2bf(cc < 7 ? c1w[((o * 4 + c) * 7 + r) * 7 + cc] : 0.0f);
  }
  if (i < CH2 * CH2) {
    int o = i >> 10, k = i & 1023;
    int pos = k >> 8, ci = k & 255;
    w2p[i] = f2bf(c2w[(size_t)(o * 256 + ci) * 4 + pos]);
  }
}

// ---- point -> bilinear weight accumulation (LDS-aggregated, G12) ----
__global__ __launch_bounds__(256) void k_pts(const float* __restrict__ coords,
                                             float* __restrict__ Aw,
                                             float* __restrict__ cnt,
                                             float* __restrict__ sumAw) {
  __shared__ float lAw[NLOC];
  __shared__ int lcnt;
  __shared__ float wsum[4];
  int t = threadIdx.x;
  int b = blockIdx.x / 49;
  int blk = blockIdx.x - b * 49;
  for (int i = t; i < NLOC; i += 256) lAw[i] = 0.f;
  if (t == 0) lcnt = 0;
  __syncthreads();
  int pi = blk * 256 + t;
  float x = coords[((size_t)b * NPTS + pi) * 2];
  float y = coords[((size_t)b * NPTS + pi) * 2 + 1];
  bool valid = (x >= 0.0f);
  if (valid) {
    float gx = x * 32.0f - 0.5f, gy = y * 32.0f - 0.5f;
    float x0f = floorf(gx), y0f = floorf(gy);
    int x0 = (int)x0f, y0 = (int)y0f;
    float wx1 = gx - x0f, wx0 = 1.0f - wx1;
    float wy1 = gy - y0f, wy0 = 1.0f - wy1;
    int xs[2] = {x0, x0 + 1}, ys[2] = {y0, y0 + 1};
    float wxs[2] = {wx0, wx1}, wys[2] = {wy0, wy1};
    #pragma unroll
    for (int cy = 0; cy < 2; cy++)
      #pragma unroll
      for (int cx = 0; cx < 2; cx++) {
        int ix = xs[cx], iy = ys[cy];
        if (ix >= 0 && ix < 32 && iy >= 0 && iy < 32)
          atomicAdd(&lAw[iy * 32 + ix], wxs[cx] * wys[cy]);
      }
  }
  unsigned long long ball = __ballot(valid);
  if ((t & 63) == 0) atomicAdd(&lcnt, (int)__popcll(ball));
  __syncthreads();
  float tsum = 0.f;
  for (int i = t; i < NLOC; i += 256) {
    float v = lAw[i];
    tsum += v;
    if (v != 0.f) atomicAdd(&Aw[b * NLOC + i], v);
  }
  #pragma unroll
  for (int m = 1; m <= 32; m <<= 1) tsum += __shfl_xor(tsum, m, 64);
  if ((t & 63) == 0) wsum[t >> 6] = tsum;
  __syncthreads();
  if (t == 0) {
    float bs = wsum[0] + wsum[1] + wsum[2] + wsum[3];
    if (bs != 0.f) atomicAdd(&sumAw[b], bs);
    if (lcnt) atomicAdd(&cnt[b], (float)lcnt);
  }
}

// ---- active-row compaction: ordered (deterministic) per-batch prefix scan ----
// idxc[b*CAP+i] = i-th active row id (Aw != 0), Awc = its weight; padded with
// (row b*1024, weight 0) to CAP. One block; Hillis-Steele scan in LDS.
__global__ __launch_bounds__(256) void k_compact(const float* __restrict__ Aw,
                                                 int* __restrict__ idxc,
                                                 float* __restrict__ Awc) {
  __shared__ int cnts[256], offs[256];
  int t = threadIdx.x;
  for (int b = 0; b < NB; b++) {
    int base = b * 1024 + t * 4;
    float w[4];
    int c = 0;
    #pragma unroll
    for (int j = 0; j < 4; j++) { w[j] = Aw[base + j]; c += (w[j] != 0.f) ? 1 : 0; }
    cnts[t] = c;
    offs[t] = c;
    __syncthreads();
    for (int s = 1; s < 256; s <<= 1) {
      int v = (t >= s) ? offs[t - s] : 0;
      __syncthreads();
      offs[t] += v;
      __syncthreads();
    }
    int pos = b * CAP + offs[t] - cnts[t];
    int lim = (b + 1) * CAP;
    #pragma unroll
    for (int j = 0; j < 4; j++)
      if (w[j] != 0.f && pos < lim) { idxc[pos] = base + j; Awc[pos] = w[j]; pos++; }
    int total = offs[255];
    for (int i = total + t; i < CAP; i += 256) {
      idxc[b * CAP + i] = b * 1024;
      Awc[b * CAP + i] = 0.f;
    }
    __syncthreads();
  }
}

// ---- im2col for conv1 (7x7 s7, zero duplication) ----
__global__ __launch_bounds__(256) void k_im2col(const float* __restrict__ images,
                                                const float* __restrict__ masks,
                                                short* __restrict__ A1g) {
  __shared__ float S[28 * 452];
  int t = threadIdx.x;
  int b = blockIdx.x >> 6, y = blockIdx.x & 63;
  int y7 = y * 7;
  for (int p = t; p < 3136; p += 256) {
    int row = p / 112, c4 = p - row * 112;
    int c = row / 7, r = row - c * 7;
    const float* src = (c < 3)
        ? &images[((size_t)(b * 3 + c) * 448 + y7 + r) * 448 + c4 * 4]
        : &masks[((size_t)b * 448 + y7 + r) * 448 + c4 * 4];
    *(float4*)&S[row * 452 + c4 * 4] = *(const float4*)src;
  }
  __syncthreads();
  size_t obase = (size_t)blockIdx.x * 64 * K1;
  #pragma unroll
  for (int it = 0; it < 7; it++) {
    int p = it * 256 + t;
    int x = p / 28, k16 = p - x * 28;
    const float* s = &S[k16 * 452 + x * 7];
    short o[8];
    #pragma unroll
    for (int j = 0; j < 7; j++) o[j] = f2bf(s[j]);
    o[7] = 0;
    *(bf16x8*)&A1g[obase + (size_t)p * 8] = *(bf16x8*)o;
  }
}

// ---- bf16 BT GEMM, 128x64 tile, BK=32, 2-phase dbuf; bf16 transposed store ----
// PROVEN structure (R6/R7). 64-row-tile fused variants all failed (R0/R2/R8).
template<int KDIM>
__global__ __launch_bounds__(256) void k_gemm(
    const short* __restrict__ Amat, const short* __restrict__ Bmat,
    const float* __restrict__ bias, short* __restrict__ Cout, int ldc) {
  __shared__ __align__(16) char Lraw[24576];
  int t = threadIdx.x, lane = t & 63, wv = t >> 6;
  int mt0 = blockIdx.x * 128;
  int nt0 = blockIdx.y * 64;
  f32x4 acc[4][2];
  #pragma unroll
  for (int i = 0; i < 4; i++)
    #pragma unroll
    for (int j = 0; j < 2; j++) acc[i][j] = (f32x4){0.f, 0.f, 0.f, 0.f};

  int srow = lane >> 2, scol = (lane & 3) * 8;
  int wm = wv >> 1, wn = wv & 1;
  int l15 = lane & 15, lg = lane >> 4;
  int r0 = wv * 16, r1 = 64 + wv * 16;

  auto STAGE = [&](int buf, int kt) {
    int k0 = kt * 32;
    char* As = Lraw + buf * 12288;
    char* Bs = As + 8192;
    gload_lds16(&Amat[(size_t)(mt0 + r0 + srow) * KDIM + k0 + scol], As + r0 * 64);
    gload_lds16(&Amat[(size_t)(mt0 + r1 + srow) * KDIM + k0 + scol], As + r1 * 64);
    gload_lds16(&Bmat[(size_t)(nt0 + r0 + srow) * KDIM + k0 + scol], Bs + r0 * 64);
  };

  const int NT = KDIM / 32;
  STAGE(0, 0);
  __syncthreads();
  int cur = 0;
  #pragma unroll 2
  for (int kt = 0; kt < NT; kt++) {
    if (kt + 1 < NT) STAGE(cur ^ 1, kt + 1);
    const short* As = (const short*)(Lraw + cur * 12288);
    const short* Bs = As + 4096;
    bf16x8 af[4], bfr[2];
    #pragma unroll
    for (int i = 0; i < 4; i++)
      af[i] = *(const bf16x8*)&As[(wm * 64 + i * 16 + l15) * 32 + lg * 8];
    #pragma unroll
    for (int j = 0; j < 2; j++)
      bfr[j] = *(const bf16x8*)&Bs[(wn * 32 + j * 16 + l15) * 32 + lg * 8];
    #pragma unroll
    for (int i = 0; i < 4; i++)
      #pragma unroll
      for (int j = 0; j < 2; j++)
        acc[i][j] = __builtin_amdgcn_mfma_f32_16x16x32_bf16(af[i], bfr[j], acc[i][j], 0, 0, 0);
    __syncthreads();
    cur ^= 1;
  }

  short* ct = (short*)Lraw;
  #pragma unroll
  for (int i = 0; i < 4; i++)
    #pragma unroll
    for (int j = 0; j < 2; j++) {
      int cl = wn * 32 + j * 16 + l15;
      float bv = bias[nt0 + cl];
      #pragma unroll
      for (int reg = 0; reg < 4; reg++) {
        int rl = wm * 64 + i * 16 + lg * 4 + reg;
        ct[rl * 68 + cl] = f2bf(acc[i][j][reg] + bv);
      }
    }
  __syncthreads();
  #pragma unroll
  for (int it = 0; it < 4; it++) {
    int p = it * 256 + t;
    int row = p >> 3, cc = (p & 7) * 8;
    bf16x8 v = *(const bf16x8*)&ct[row * 68 + cc];
    *(bf16x8*)&Cout[(size_t)(mt0 + row) * ldc + nt0 + cc] = v;
  }
}

// ---- conv2 GEMM on COMPACTED rows: A-rows gathered via idxc ----
__global__ __launch_bounds__(256) void k_gemmc(
    const short* __restrict__ Amat, const int* __restrict__ idxc,
    const short* __restrict__ Bmat, const float* __restrict__ bias,
    short* __restrict__ Cout) {
  const int KDIM = 1024, ldc = 1024;
  __shared__ __align__(16) char Lraw[24576];
  int t = threadIdx.x, lane = t & 63, wv = t >> 6;
  int mt0 = blockIdx.x * 128;
  int nt0 = blockIdx.y * 64;
  f32x4 acc[4][2];
  #pragma unroll
  for (int i = 0; i < 4; i++)
    #pragma unroll
    for (int j = 0; j < 2; j++) acc[i][j] = (f32x4){0.f, 0.f, 0.f, 0.f};

  int srow = lane >> 2, scol = (lane & 3) * 8;
  int wm = wv >> 1, wn = wv & 1;
  int l15 = lane & 15, lg = lane >> 4;
  int r0 = wv * 16, r1 = 64 + wv * 16;
  // per-lane A-row gather indices (constant over K loop)
  const short* Ap0 = Amat + (size_t)idxc[mt0 + r0 + srow] * KDIM;
  const short* Ap1 = Amat + (size_t)idxc[mt0 + r1 + srow] * KDIM;

  auto STAGE = [&](int buf, int kt) {
    int k0 = kt * 32;
    char* As = Lraw + buf * 12288;
    char* Bs = As + 8192;
    gload_lds16(Ap0 + k0 + scol, As + r0 * 64);
    gload_lds16(Ap1 + k0 + scol, As + r1 * 64);
    gload_lds16(&Bmat[(size_t)(nt0 + r0 + srow) * KDIM + k0 + scol], Bs + r0 * 64);
  };

  STAGE(0, 0);
  __syncthreads();
  int cur = 0;
  #pragma unroll 2
  for (int kt = 0; kt < 32; kt++) {
    if (kt + 1 < 32) STAGE(cur ^ 1, kt + 1);
    const short* As = (const short*)(Lraw + cur * 12288);
    const short* Bs = As + 4096;
    bf16x8 af[4], bfr[2];
    #pragma unroll
    for (int i = 0; i < 4; i++)
      af[i] = *(const bf16x8*)&As[(wm * 64 + i * 16 + l15) * 32 + lg * 8];
    #pragma unroll
    for (int j = 0; j < 2; j++)
      bfr[j] = *(const bf16x8*)&Bs[(wn * 32 + j * 16 + l15) * 32 + lg * 8];
    #pragma unroll
    for (int i = 0; i < 4; i++)
      #pragma unroll
      for (int j = 0; j < 2; j++)
        acc[i][j] = __builtin_amdgcn_mfma_f32_16x16x32_bf16(af[i], bfr[j], acc[i][j], 0, 0, 0);
    __syncthreads();
    cur ^= 1;
  }

  short* ct = (short*)Lraw;
  #pragma unroll
  for (int i = 0; i < 4; i++)
    #pragma unroll
    for (int j = 0; j < 2; j++) {
      int cl = wn * 32 + j * 16 + l15;
      float bv = bias[nt0 + cl];
      #pragma unroll
      for (int reg = 0; reg < 4; reg++) {
        int rl = wm * 64 + i * 16 + lg * 4 + reg;
        ct[rl * 68 + cl] = f2bf(acc[i][j][reg] + bv);
      }
    }
  __syncthreads();
  #pragma unroll
  for (int it = 0; it < 4; it++) {
    int p = it * 256 + t;
    int row = p >> 3, cc = (p & 7) * 8;
    bf16x8 v = *(const bf16x8*)&ct[row * 68 + cc];
    *(bf16x8*)&Cout[(size_t)(mt0 + row) * ldc + nt0 + cc] = v;
  }
}

// ---- LN(256)+GELU on y1 rows, scatter to conv2-im2col layout ----
__global__ __launch_bounds__(256) void k_ln1(const short* __restrict__ y1,
                                             const float* __restrict__ ln1w,
                                             const float* __restrict__ ln1b,
                                             short* __restrict__ act1) {
  int t = threadIdx.x, wv = t >> 6, lane = t & 63;
  int c = lane * 4;
  float lw[4], lb[4];
  #pragma unroll
  for (int j = 0; j < 4; j++) { lw[j] = ln1w[c + j]; lb[j] = ln1b[c + j]; }
  int m0 = blockIdx.x * 64 + wv * 16;
  for (int r = 0; r < 16; r++) {
    int m = m0 + r;
    short4 v4 = *(const short4*)&y1[(size_t)m * 256 + c];
    float xs[4] = {bf2f(v4.x), bf2f(v4.y), bf2f(v4.z), bf2f(v4.w)};
    float s = 0.f, q = 0.f;
    #pragma unroll
    for (int j = 0; j < 4; j++) { s += xs[j]; q += xs[j] * xs[j]; }
    #pragma unroll
    for (int mm = 1; mm <= 32; mm <<= 1) { s += __shfl_xor(s, mm, 64); q += __shfl_xor(q, mm, 64); }
    float u = s * (1.0f / 256.0f);
    float rs = rsqrtf(q * (1.0f / 256.0f) - u * u + 1e-6f);
    short o[4];
    #pragma unroll
    for (int j = 0; j < 4; j++) o[j] = f2bf(gelu_f(lw[j] * ((xs[j] - u) * rs) + lb[j]));
    int b = m >> 12, y = (m >> 6) & 63, x = m & 63;
    size_t row = (size_t)(b * 32 + (y >> 1)) * 32 + (x >> 1);
    size_t addr = row * 1024 + (size_t)((y & 1) * 2 + (x & 1)) * 256 + c;
    *(short4*)&act1[addr] = make_short4(o[0], o[1], o[2], o[3]);
  }
}

// ---- fused LN(1024)+GELU+weighted-pool over COMPACTED rows, atomic-free ----
// 96 blocks = 8 batches x 12 chunks x 32 rows; one wave per row.
__global__ __launch_bounds__(256) void k_ln2poolp(const short* __restrict__ y2c,
                                                  const float* __restrict__ ln2w,
                                                  const float* __restrict__ ln2b,
                                                  const float* __restrict__ Awc,
                                                  float* __restrict__ partials) {
  int t = threadIdx.x, wv = t >> 6, lane = t & 63;
  int b = blockIdx.x / 12, chunk = blockIdx.x % 12;
  int base = b * CAP + chunk * 32;
  int c0 = lane * 16;
  float lw[16], lb[16], wacc[16];
  #pragma unroll
  for (int j = 0; j < 16; j++) {
    lw[j] = ln2w[c0 + j];
    lb[j] = ln2b[c0 + j];
    wacc[j] = 0.f;
  }
  for (int pass = 0; pass < 8; pass++) {
    int row = base + pass * 4 + wv;
    float wt = Awc[row];
    if (wt == 0.f) continue;            // wave-uniform skip (padding rows)
    bf16x8 v0 = *(const bf16x8*)&y2c[(size_t)row * 1024 + c0];
    bf16x8 v1 = *(const bf16x8*)&y2c[(size_t)row * 1024 + c0 + 8];
    float xs[16];
    #pragma unroll
    for (int j = 0; j < 8; j++) { xs[j] = bf2f(v0[j]); xs[8 + j] = bf2f(v1[j]); }
    float s = 0.f, q = 0.f;
    #pragma unroll
    for (int j = 0; j < 16; j++) { s += xs[j]; q += xs[j] * xs[j]; }
    #pragma unroll
    for (int m = 1; m <= 32; m <<= 1) { s += __shfl_xor(s, m, 64); q += __shfl_xor(q, m, 64); }
    float u = s * (1.0f / 1024.0f);
    float rs = rsqrtf(q * (1.0f / 1024.0f) - u * u + 1e-6f);
    #pragma unroll
    for (int j = 0; j < 16; j++)
      wacc[j] += wt * gelu_f(lw[j] * ((xs[j] - u) * rs) + lb[j]);
  }
  float* dst = &partials[((size_t)blockIdx.x * 4 + wv) * 1024 + c0];
  #pragma unroll
  for (int j = 0; j < 4; j++)
    *(f32x4*)&dst[j * 4] = (f32x4){wacc[j * 4], wacc[j * 4 + 1], wacc[j * 4 + 2], wacc[j * 4 + 3]};
}

// ---- weighted pool over feat rows gathered via idxc, atomic-free ----
__global__ __launch_bounds__(256) void k_poolfp(const float* __restrict__ feat,
                                                const int* __restrict__ idxc,
                                                const float* __restrict__ Awc,
                                                float* __restrict__ partialsF) {
  int t = threadIdx.x, wv = t >> 6, lane = t & 63;
  int b = blockIdx.x / 12, chunk = blockIdx.x % 12;
  int base = b * CAP + chunk * 32;
  int c0 = lane * 16;
  float wacc[16];
  #pragma unroll
  for (int j = 0; j < 16; j++) wacc[j] = 0.f;
  for (int pass = 0; pass < 8; pass++) {
    int row = base + pass * 4 + wv;
    float wt = Awc[row];
    if (wt == 0.f) continue;
    const float4* fp = (const float4*)(feat + (size_t)idxc[row] * 1024 + c0);
    #pragma unroll
    for (int j = 0; j < 4; j++) {
      float4 v = fp[j];
      wacc[j * 4 + 0] += wt * v.x;
      wacc[j * 4 + 1] += wt * v.y;
      wacc[j * 4 + 2] += wt * v.z;
      wacc[j * 4 + 3] += wt * v.w;
    }
  }
  float* dst = &partialsF[((size_t)blockIdx.x * 4 + wv) * 1024 + c0];
  #pragma unroll
  for (int j = 0; j < 4; j++)
    *(f32x4*)&dst[j * 4] = (f32x4){wacc[j * 4], wacc[j * 4 + 1], wacc[j * 4 + 2], wacc[j * 4 + 3]};
}

// ---- reduce both partial arrays: 48 slots per batch each ----
__global__ __launch_bounds__(256) void k_red(const float* __restrict__ partials,
                                             const float* __restrict__ partialsF,
                                             float* __restrict__ pa,
                                             float* __restrict__ pf) {
  int c = blockIdx.x * 256 + threadIdx.x;   // 0..8191
  int b = c >> 10, ch = c & 1023;
  const float* p = partials + (size_t)(b * 48) * 1024 + ch;
  const float* pF = partialsF + (size_t)(b * 48) * 1024 + ch;
  float s = 0.f, sf = 0.f;
  #pragma unroll 8
  for (int j = 0; j < 48; j++) {
    s += p[(size_t)j * 1024];
    sf += pF[(size_t)j * 1024];
  }
  pa[c] = s;
  pf[c] = sf;
}

// ---- conv3 folded past the pool ----
__global__ __launch_bounds__(256) void k_mix(const float* __restrict__ pa,
                                             const float* __restrict__ pf,
                                             const float* __restrict__ sumAw,
                                             const float* __restrict__ cnt,
                                             const float* __restrict__ c3w,
                                             const float* __restrict__ c3b,
                                             float* __restrict__ zn) {
  int t = threadIdx.x, wv = t >> 6, lane = t & 63;
  int idx = blockIdx.x * 4 + wv;   // 0..8191 = b*1024 + c
  int b = idx >> 10, c = idx & 1023;
  float s = 0.f;
  #pragma unroll
  for (int i = 0; i < 16; i++) {
    int k = i * 64 + lane;
    s += c3w[(size_t)c * 1024 + k] * pa[b * 1024 + k];
  }
  #pragma unroll
  for (int m = 1; m <= 32; m <<= 1) s += __shfl_xor(s, m, 64);
  if (lane == 0) {
    float z = s + sumAw[b] * c3b[c] + pf[idx];
    float cv = cnt[b];
    zn[idx] = cv > 0.f ? z / cv : 0.f;   // nan_to_num
  }
}

// ---- final GEMV: 1024 blocks, one wave per output row, 8 batches/wave ----
__global__ __launch_bounds__(256) void k_out(const float* __restrict__ zn,
                                             const float* __restrict__ up_w,
                                             const float* __restrict__ up_b,
                                             float* __restrict__ out) {
  __shared__ float pl[8192];
  int t = threadIdx.x;
  for (int idx = t; idx < 2048; idx += 256)
    ((float4*)pl)[idx] = ((const float4*)zn)[idx];
  __syncthreads();
  int wv = t >> 6, lane = t & 63;
  int o = blockIdx.x * 4 + wv;
  float w[16];
  #pragma unroll
  for (int i = 0; i < 16; i++) w[i] = up_w[(size_t)o * 1024 + i * 64 + lane];
  float s[8];
  #pragma unroll
  for (int b = 0; b < 8; b++) s[b] = 0.f;
  #pragma unroll
  for (int i = 0; i < 16; i++) {
    int k = i * 64 + lane;
    #pragma unroll
    for (int b = 0; b < 8; b++) s[b] += w[i] * pl[b * 1024 + k];
  }
  #pragma unroll
  for (int m = 1; m <= 32; m <<= 1)
    #pragma unroll
    for (int b = 0; b < 8; b++) s[b] += __shfl_xor(s[b], m, 64);
  if (lane < 8) out[(size_t)lane * NOUT + o] = s[lane] + up_b[o];
}

extern "C" void kernel_launch(void* const* d_in, const int* in_sizes, int n_in,
                              void* d_out, int out_size, void* d_ws, size_t ws_size,
                              hipStream_t stream) {
  const float* images = (const float*)d_in[0];
  const float* masks  = (const float*)d_in[1];
  const float* feat   = (const float*)d_in[2];   // [B,1024(loc),1024(emb)]
  const float* coords = (const float*)d_in[3];
  const float* c1w  = (const float*)d_in[5];
  const float* c1b  = (const float*)d_in[6];
  const float* ln1w = (const float*)d_in[7];
  const float* ln1b = (const float*)d_in[8];
  const float* c2w  = (const float*)d_in[9];
  const float* c2b  = (const float*)d_in[10];
  const float* ln2w = (const float*)d_in[11];
  const float* ln2b = (const float*)d_in[12];
  const float* c3w  = (const float*)d_in[13];
  const float* c3b  = (const float*)d_in[14];
  const float* up_w = (const float*)d_in[15];
  const float* up_b = (const float*)d_in[16];
  float* out = (float*)d_out;

  char* ws = (char*)d_ws;
  size_t off = 0;
  auto alloc = [&](size_t bytes) -> void* {
    void* p = ws + off;
    off = (off + bytes + 255) & ~(size_t)255;
    return p;
  };
  float* Aw    = (float*)alloc(8192 * 4);
  float* cnt   = (float*)alloc(8 * 4);
  float* sumAw = (float*)alloc(8 * 4);
  size_t zeroBytes = off;
  int*   idxc  = (int*)alloc(MC * 4);
  float* Awc   = (float*)alloc(MC * 4);
  float* pa    = (float*)alloc(8192 * 4);
  float* pf    = (float*)alloc(8192 * 4);
  float* partials  = (float*)alloc((size_t)384 * 1024 * 4);   // [96*4][1024]
  float* partialsF = (float*)alloc((size_t)384 * 1024 * 4);
  float* zn   = (float*)alloc(8192 * 4);
  short* c1wb = (short*)alloc((size_t)CH1 * K1 * 2);
  short* w2p  = (short*)alloc((size_t)CH2 * CH2 * 2);
  short* act1 = (short*)alloc((size_t)M2 * 1024 * 2);
  short* slotB = (short*)alloc((size_t)M2 * 1024 * 2);  // A1g then y2c
  short* y1   = (short*)alloc((size_t)M1 * 256 * 2);    // conv1 pre-LN out
  short* A1g  = slotB;   // im2col, dead before conv2 writes y2c
  short* y2c  = slotB;   // compacted conv2 out [MC][1024]

  int n4 = (int)(zeroBytes / 16);
  k_zero<<<(n4 + 255) / 256, 256, 0, stream>>>((float4*)d_ws, n4);
  k_wcast<<<4096, 256, 0, stream>>>(c1w, c2w, c1wb, w2p);
  k_pts<<<NB * 49, 256, 0, stream>>>(coords, Aw, cnt, sumAw);
  k_compact<<<1, 256, 0, stream>>>(Aw, idxc, Awc);
  k_im2col<<<512, 256, 0, stream>>>(images, masks, A1g);
  k_gemm<K1><<<dim3(M1 / 128, 4), 256, 0, stream>>>(A1g, c1wb, c1b, y1, 256);
  k_ln1<<<M1 / 64, 256, 0, stream>>>(y1, ln1w, ln1b, act1);
  k_gemmc<<<dim3(MC / 128, 16), 256, 0, stream>>>(act1, idxc, w2p, c2b, y2c);
  k_ln2poolp<<<96, 256, 0, stream>>>(y2c, ln2w, ln2b, Awc, partials);
  k_poolfp<<<96, 256, 0, stream>>>(feat, idxc, Awc, partialsF);
  k_red<<<32, 256, 0, stream>>>(partials, partialsF, pa, pf);
  k_mix<<<2048, 256, 0, stream>>>(pa, pf, sumAw, cnt, c3w, c3b, zn);
  k_out<<<NOUT / 4, 256, 0, stream>>>(zn, up_w, up_b, out);
}

// Round 13
// 119.646 us; speedup vs baseline: 1.4094x; 1.1809x over previous
//
#include <hip/hip_runtime.h>
#include <stdint.h>

// Problem constants
#define NB 8
#define HIN 448
#define CH1 256
#define CH2 1024
#define NLOC 1024        // 32*32
#define M2 8192          // NB*NLOC
#define M1 32768         // NB*64*64 conv1 output locations
#define K1 224           // padded im2col K: c*56 + r*8 + cc(0..7), cc==7 -> 0
#define NPTS 12544
#define NOUT 4096
#define CAP 384          // per-batch compacted-row capacity (>= 18*18=324 bound)
#define MC (NB * CAP)    // 3072 compacted conv2 rows
#define M1C (MC * 4)     // 12288 compacted conv1 rows (4 kh/kw positions per loc)

typedef __attribute__((ext_vector_type(8))) short bf16x8;
typedef __attribute__((ext_vector_type(4))) float f32x4;

__device__ __forceinline__ short f2bf(float f) {
  uint32_t u = __builtin_bit_cast(uint32_t, f);
  uint32_t r = (u + 0x7fffu + ((u >> 16) & 1u)) >> 16;
  return (short)r;
}
__device__ __forceinline__ float bf2f(short s) {
  return __builtin_bit_cast(float, (uint32_t)(uint16_t)s << 16);
}
__device__ __forceinline__ float gelu_f(float x) {
  return 0.5f * x * (1.0f + erff(x * 0.70710678118654752f));
}
__device__ __forceinline__ void gload_lds16(const void* g, void* l) {
  __builtin_amdgcn_global_load_lds((const __attribute__((address_space(1))) unsigned int*)g,
                                   (__attribute__((address_space(3))) unsigned int*)l, 16, 0, 0);
}

// ---- fast workspace zero ----
__global__ void k_zero(float4* __restrict__ p, int n4) {
  int i = blockIdx.x * 256 + threadIdx.x;
  if (i < n4) p[i] = make_float4(0.f, 0.f, 0.f, 0.f);
}

// ---- weight prep: cast/permute into bf16 ----
__global__ void k_wcast(const float* __restrict__ c1w, const float* __restrict__ c2w,
                        short* __restrict__ c1wb, short* __restrict__ w2p) {
  int i = blockIdx.x * 256 + threadIdx.x;
  if (i < CH1 * K1) {
    int o = i / K1, k = i - o * K1;
    int c = k / 56, kk = k - c * 56, r = kk >> 3, cc = kk & 7;
    c1wb[i] = f2bf(cc < 7 ? c1w[((o * 4 + c) * 7 + r) * 7 + cc] : 0.0f);
  }
  if (i < CH2 * CH2) {
    int o = i >> 10, k = i & 1023;
    int pos = k >> 8, ci = k & 255;
    w2p[i] = f2bf(c2w[(size_t)(o * 256 + ci) * 4 + pos]);
  }
}

// ---- point -> bilinear weight accumulation (LDS-aggregated, G12) ----
__global__ __launch_bounds__(256) void k_pts(const float* __restrict__ coords,
                                             float* __restrict__ Aw,
                                             float* __restrict__ cnt,
                                             float* __restrict__ sumAw) {
  __shared__ float lAw[NLOC];
  __shared__ int lcnt;
  __shared__ float wsum[4];
  int t = threadIdx.x;
  int b = blockIdx.x / 49;
  int blk = blockIdx.x - b * 49;
  for (int i = t; i < NLOC; i += 256) lAw[i] = 0.f;
  if (t == 0) lcnt = 0;
  __syncthreads();
  int pi = blk * 256 + t;
  float x = coords[((size_t)b * NPTS + pi) * 2];
  float y = coords[((size_t)b * NPTS + pi) * 2 + 1];
  bool valid = (x >= 0.0f);
  if (valid) {
    float gx = x * 32.0f - 0.5f, gy = y * 32.0f - 0.5f;
    float x0f = floorf(gx), y0f = floorf(gy);
    int x0 = (int)x0f, y0 = (int)y0f;
    float wx1 = gx - x0f, wx0 = 1.0f - wx1;
    float wy1 = gy - y0f, wy0 = 1.0f - wy1;
    int xs[2] = {x0, x0 + 1}, ys[2] = {y0, y0 + 1};
    float wxs[2] = {wx0, wx1}, wys[2] = {wy0, wy1};
    #pragma unroll
    for (int cy = 0; cy < 2; cy++)
      #pragma unroll
      for (int cx = 0; cx < 2; cx++) {
        int ix = xs[cx], iy = ys[cy];
        if (ix >= 0 && ix < 32 && iy >= 0 && iy < 32)
          atomicAdd(&lAw[iy * 32 + ix], wxs[cx] * wys[cy]);
      }
  }
  unsigned long long ball = __ballot(valid);
  if ((t & 63) == 0) atomicAdd(&lcnt, (int)__popcll(ball));
  __syncthreads();
  float tsum = 0.f;
  for (int i = t; i < NLOC; i += 256) {
    float v = lAw[i];
    tsum += v;
    if (v != 0.f) atomicAdd(&Aw[b * NLOC + i], v);
  }
  #pragma unroll
  for (int m = 1; m <= 32; m <<= 1) tsum += __shfl_xor(tsum, m, 64);
  if ((t & 63) == 0) wsum[t >> 6] = tsum;
  __syncthreads();
  if (t == 0) {
    float bs = wsum[0] + wsum[1] + wsum[2] + wsum[3];
    if (bs != 0.f) atomicAdd(&sumAw[b], bs);
    if (lcnt) atomicAdd(&cnt[b], (float)lcnt);
  }
}

// ---- active-row compaction: one block PER BATCH (parallel barriers) ----
__global__ __launch_bounds__(256) void k_compact(const float* __restrict__ Aw,
                                                 int* __restrict__ idxc,
                                                 float* __restrict__ Awc) {
  __shared__ int cnts[256], offs[256];
  int t = threadIdx.x, b = blockIdx.x;
  int base = b * 1024 + t * 4;
  float w[4];
  int c = 0;
  #pragma unroll
  for (int j = 0; j < 4; j++) { w[j] = Aw[base + j]; c += (w[j] != 0.f) ? 1 : 0; }
  cnts[t] = c;
  offs[t] = c;
  __syncthreads();
  for (int s = 1; s < 256; s <<= 1) {
    int v = (t >= s) ? offs[t - s] : 0;
    __syncthreads();
    offs[t] += v;
    __syncthreads();
  }
  int pos = b * CAP + offs[t] - cnts[t];
  int lim = (b + 1) * CAP;
  #pragma unroll
  for (int j = 0; j < 4; j++)
    if (w[j] != 0.f && pos < lim) { idxc[pos] = base + j; Awc[pos] = w[j]; pos++; }
  int total = offs[255];
  for (int i = total + t; i < CAP; i += 256) {
    idxc[b * CAP + i] = b * 1024;
    Awc[b * CAP + i] = 0.f;
  }
}

// ---- im2col for conv1 (7x7 s7, zero duplication) ----
__global__ __launch_bounds__(256) void k_im2col(const float* __restrict__ images,
                                                const float* __restrict__ masks,
                                                short* __restrict__ A1g) {
  __shared__ float S[28 * 452];
  int t = threadIdx.x;
  int b = blockIdx.x >> 6, y = blockIdx.x & 63;
  int y7 = y * 7;
  for (int p = t; p < 3136; p += 256) {
    int row = p / 112, c4 = p - row * 112;
    int c = row / 7, r = row - c * 7;
    const float* src = (c < 3)
        ? &images[((size_t)(b * 3 + c) * 448 + y7 + r) * 448 + c4 * 4]
        : &masks[((size_t)b * 448 + y7 + r) * 448 + c4 * 4];
    *(float4*)&S[row * 452 + c4 * 4] = *(const float4*)src;
  }
  __syncthreads();
  size_t obase = (size_t)blockIdx.x * 64 * K1;
  #pragma unroll
  for (int it = 0; it < 7; it++) {
    int p = it * 256 + t;
    int x = p / 28, k16 = p - x * 28;
    const float* s = &S[k16 * 452 + x * 7];
    short o[8];
    #pragma unroll
    for (int j = 0; j < 7; j++) o[j] = f2bf(s[j]);
    o[7] = 0;
    *(bf16x8*)&A1g[obase + (size_t)p * 8] = *(bf16x8*)o;
  }
}

// ---- 64x64-tile bf16 BT GEMM, BK=32, 2-phase dbuf, bf16 transposed store ----
// MODE 0: linear A rows.  MODE 1: conv1-compacted gather (row j -> A1g row of
// (b, 2*oy+kh, 2*ox+kw) where j=(i<<2)|pos, loc=idxc[i]).
template<int KDIM, int LDC, int MODE>
__global__ __launch_bounds__(256) void k_gemm64(
    const short* __restrict__ Amat, const int* __restrict__ idxc,
    const short* __restrict__ Bmat, const float* __restrict__ bias,
    short* __restrict__ Cout) {
  __shared__ __align__(16) char Lraw[16384];  // 2 x (A 4K + B 4K); epi ct[64][68]=8.7K
  int t = threadIdx.x, lane = t & 63, wv = t >> 6;
  int mt0 = blockIdx.x * 64;
  int nt0 = blockIdx.y * 64;
  f32x4 acc[2][2];
  #pragma unroll
  for (int i = 0; i < 2; i++)
    #pragma unroll
    for (int j = 0; j < 2; j++) acc[i][j] = (f32x4){0.f, 0.f, 0.f, 0.f};

  int srow = lane >> 2, scol = (lane & 3) * 8;
  int wm = wv >> 1, wn = wv & 1;
  int l15 = lane & 15, lg = lane >> 4;

  int arow = mt0 + wv * 16 + srow;   // A row this lane stages
  const short* Ap;
  if (MODE == 1) {
    int i = arow >> 2, pos = arow & 3;
    int loc = idxc[i];
    int b = loc >> 10, oy = (loc >> 5) & 31, ox = loc & 31;
    int yy = oy * 2 + (pos >> 1), xx = ox * 2 + (pos & 1);
    Ap = Amat + (size_t)((b * 64 + yy) * 64 + xx) * KDIM;
  } else {
    Ap = Amat + (size_t)arow * KDIM;
  }
  const short* Bp = Bmat + (size_t)(nt0 + wv * 16 + srow) * KDIM;

  auto STAGE = [&](int buf, int kt) {
    int k0 = kt * 32;
    char* As = Lraw + buf * 8192;
    char* Bs = As + 4096;
    gload_lds16(Ap + k0 + scol, As + wv * 1024);
    gload_lds16(Bp + k0 + scol, Bs + wv * 1024);
  };

  const int NT = KDIM / 32;
  STAGE(0, 0);
  __syncthreads();
  int cur = 0;
  #pragma unroll 2
  for (int kt = 0; kt < NT; kt++) {
    if (kt + 1 < NT) STAGE(cur ^ 1, kt + 1);
    const short* As = (const short*)(Lraw + cur * 8192);
    const short* Bs = As + 2048;
    bf16x8 af[2], bfr[2];
    #pragma unroll
    for (int i = 0; i < 2; i++)
      af[i] = *(const bf16x8*)&As[(wm * 32 + i * 16 + l15) * 32 + lg * 8];
    #pragma unroll
    for (int j = 0; j < 2; j++)
      bfr[j] = *(const bf16x8*)&Bs[(wn * 32 + j * 16 + l15) * 32 + lg * 8];
    #pragma unroll
    for (int i = 0; i < 2; i++)
      #pragma unroll
      for (int j = 0; j < 2; j++)
        acc[i][j] = __builtin_amdgcn_mfma_f32_16x16x32_bf16(af[i], bfr[j], acc[i][j], 0, 0, 0);
    __syncthreads();
    cur ^= 1;
  }

  short* ct = (short*)Lraw;
  #pragma unroll
  for (int i = 0; i < 2; i++)
    #pragma unroll
    for (int j = 0; j < 2; j++) {
      int cl = wn * 32 + j * 16 + l15;
      float bv = bias[nt0 + cl];
      #pragma unroll
      for (int reg = 0; reg < 4; reg++) {
        int rl = wm * 32 + i * 16 + lg * 4 + reg;
        ct[rl * 68 + cl] = f2bf(acc[i][j][reg] + bv);
      }
    }
  __syncthreads();
  #pragma unroll
  for (int it = 0; it < 2; it++) {
    int p = it * 256 + t;                 // 512 16B chunks
    int row = p >> 3, cc = (p & 7) * 8;
    bf16x8 v = *(const bf16x8*)&ct[row * 68 + cc];
    *(bf16x8*)&Cout[(size_t)(mt0 + row) * LDC + nt0 + cc] = v;
  }
}

// ---- LN(256)+GELU on compacted conv1 rows -> act1c[i][pos*256+ch] ----
__global__ __launch_bounds__(256) void k_ln1c(const short* __restrict__ y1c,
                                              const float* __restrict__ ln1w,
                                              const float* __restrict__ ln1b,
                                              short* __restrict__ act1c) {
  int t = threadIdx.x, wv = t >> 6, lane = t & 63;
  int c = lane * 4;
  float lw[4], lb[4];
  #pragma unroll
  for (int j = 0; j < 4; j++) { lw[j] = ln1w[c + j]; lb[j] = ln1b[c + j]; }
  int j0 = blockIdx.x * 64 + wv * 16;
  for (int r = 0; r < 16; r++) {
    int j = j0 + r;
    short4 v4 = *(const short4*)&y1c[(size_t)j * 256 + c];
    float xs[4] = {bf2f(v4.x), bf2f(v4.y), bf2f(v4.z), bf2f(v4.w)};
    float s = 0.f, q = 0.f;
    #pragma unroll
    for (int jj = 0; jj < 4; jj++) { s += xs[jj]; q += xs[jj] * xs[jj]; }
    #pragma unroll
    for (int mm = 1; mm <= 32; mm <<= 1) { s += __shfl_xor(s, mm, 64); q += __shfl_xor(q, mm, 64); }
    float u = s * (1.0f / 256.0f);
    float rs = rsqrtf(q * (1.0f / 256.0f) - u * u + 1e-6f);
    short o[4];
    #pragma unroll
    for (int jj = 0; jj < 4; jj++) o[jj] = f2bf(gelu_f(lw[jj] * ((xs[jj] - u) * rs) + lb[jj]));
    size_t addr = (size_t)(j >> 2) * 1024 + (size_t)(j & 3) * 256 + c;
    *(short4*)&act1c[addr] = make_short4(o[0], o[1], o[2], o[3]);
  }
}

// ---- merged LN(1024)+GELU+pool over y2c AND gathered-feat pool, atomic-free ----
// 96 blocks = 8 batches x 12 chunks x 32 rows; one wave per row.
__global__ __launch_bounds__(256) void k_poolboth(const short* __restrict__ y2c,
                                                  const float* __restrict__ feat,
                                                  const int* __restrict__ idxc,
                                                  const float* __restrict__ ln2w,
                                                  const float* __restrict__ ln2b,
                                                  const float* __restrict__ Awc,
                                                  float* __restrict__ partials,
                                                  float* __restrict__ partialsF) {
  int t = threadIdx.x, wv = t >> 6, lane = t & 63;
  int b = blockIdx.x / 12, chunk = blockIdx.x % 12;
  int base = b * CAP + chunk * 32;
  int c0 = lane * 16;
  float lw[16], lb[16], wacc[16], facc[16];
  #pragma unroll
  for (int j = 0; j < 16; j++) {
    lw[j] = ln2w[c0 + j];
    lb[j] = ln2b[c0 + j];
    wacc[j] = 0.f;
    facc[j] = 0.f;
  }
  for (int pass = 0; pass < 8; pass++) {
    int row = base + pass * 4 + wv;
    float wt = Awc[row];
    if (wt == 0.f) continue;            // wave-uniform skip (padding rows)
    // feat pool (gathered row)
    const float4* fp = (const float4*)(feat + (size_t)idxc[row] * 1024 + c0);
    #pragma unroll
    for (int j = 0; j < 4; j++) {
      float4 v = fp[j];
      facc[j * 4 + 0] += wt * v.x;
      facc[j * 4 + 1] += wt * v.y;
      facc[j * 4 + 2] += wt * v.z;
      facc[j * 4 + 3] += wt * v.w;
    }
    // LN+GELU pool on y2c
    bf16x8 v0 = *(const bf16x8*)&y2c[(size_t)row * 1024 + c0];
    bf16x8 v1 = *(const bf16x8*)&y2c[(size_t)row * 1024 + c0 + 8];
    float xs[16];
    #pragma unroll
    for (int j = 0; j < 8; j++) { xs[j] = bf2f(v0[j]); xs[8 + j] = bf2f(v1[j]); }
    float s = 0.f, q = 0.f;
    #pragma unroll
    for (int j = 0; j < 16; j++) { s += xs[j]; q += xs[j] * xs[j]; }
    #pragma unroll
    for (int m = 1; m <= 32; m <<= 1) { s += __shfl_xor(s, m, 64); q += __shfl_xor(q, m, 64); }
    float u = s * (1.0f / 1024.0f);
    float rs = rsqrtf(q * (1.0f / 1024.0f) - u * u + 1e-6f);
    #pragma unroll
    for (int j = 0; j < 16; j++)
      wacc[j] += wt * gelu_f(lw[j] * ((xs[j] - u) * rs) + lb[j]);
  }
  float* dst = &partials[((size_t)blockIdx.x * 4 + wv) * 1024 + c0];
  float* dstF = &partialsF[((size_t)blockIdx.x * 4 + wv) * 1024 + c0];
  #pragma unroll
  for (int j = 0; j < 4; j++) {
    *(f32x4*)&dst[j * 4] = (f32x4){wacc[j * 4], wacc[j * 4 + 1], wacc[j * 4 + 2], wacc[j * 4 + 3]};
    *(f32x4*)&dstF[j * 4] = (f32x4){facc[j * 4], facc[j * 4 + 1], facc[j * 4 + 2], facc[j * 4 + 3]};
  }
}

// ---- reduce both partial arrays: 48 slots per batch each ----
__global__ __launch_bounds__(256) void k_red(const float* __restrict__ partials,
                                             const float* __restrict__ partialsF,
                                             float* __restrict__ pa,
                                             float* __restrict__ pf) {
  int c = blockIdx.x * 256 + threadIdx.x;   // 0..8191
  int b = c >> 10, ch = c & 1023;
  const float* p = partials + (size_t)(b * 48) * 1024 + ch;
  const float* pF = partialsF + (size_t)(b * 48) * 1024 + ch;
  float s = 0.f, sf = 0.f;
  #pragma unroll 8
  for (int j = 0; j < 48; j++) {
    s += p[(size_t)j * 1024];
    sf += pF[(size_t)j * 1024];
  }
  pa[c] = s;
  pf[c] = sf;
}

// ---- conv3 folded past the pool: wave-per-channel, c3w read once ----
__global__ __launch_bounds__(256) void k_mix(const float* __restrict__ pa,
                                             const float* __restrict__ pf,
                                             const float* __restrict__ sumAw,
                                             const float* __restrict__ cnt,
                                             const float* __restrict__ c3w,
                                             const float* __restrict__ c3b,
                                             float* __restrict__ zn) {
  __shared__ float pl[8192];
  int t = threadIdx.x;
  for (int idx = t; idx < 2048; idx += 256)
    ((float4*)pl)[idx] = ((const float4*)pa)[idx];
  __syncthreads();
  int wv = t >> 6, lane = t & 63;
  int c = blockIdx.x * 4 + wv;
  float w[16];
  #pragma unroll
  for (int i = 0; i < 16; i++) w[i] = c3w[(size_t)c * 1024 + i * 64 + lane];
  float s[8];
  #pragma unroll
  for (int b = 0; b < 8; b++) s[b] = 0.f;
  #pragma unroll
  for (int i = 0; i < 16; i++) {
    int k = i * 64 + lane;
    #pragma unroll
    for (int b = 0; b < 8; b++) s[b] += w[i] * pl[b * 1024 + k];
  }
  #pragma unroll
  for (int m = 1; m <= 32; m <<= 1)
    #pragma unroll
    for (int b = 0; b < 8; b++) s[b] += __shfl_xor(s[b], m, 64);
  if (lane < 8) {
    float cv = cnt[lane];
    float z = s[lane] + sumAw[lane] * c3b[c] + pf[lane * 1024 + c];
    zn[lane * 1024 + c] = cv > 0.f ? z / cv : 0.f;   // nan_to_num
  }
}

// ---- final GEMV: 1024 blocks, one wave per output row, 8 batches/wave ----
__global__ __launch_bounds__(256) void k_out(const float* __restrict__ zn,
                                             const float* __restrict__ up_w,
                                             const float* __restrict__ up_b,
                                             float* __restrict__ out) {
  __shared__ float pl[8192];
  int t = threadIdx.x;
  for (int idx = t; idx < 2048; idx += 256)
    ((float4*)pl)[idx] = ((const float4*)zn)[idx];
  __syncthreads();
  int wv = t >> 6, lane = t & 63;
  int o = blockIdx.x * 4 + wv;
  float w[16];
  #pragma unroll
  for (int i = 0; i < 16; i++) w[i] = up_w[(size_t)o * 1024 + i * 64 + lane];
  float s[8];
  #pragma unroll
  for (int b = 0; b < 8; b++) s[b] = 0.f;
  #pragma unroll
  for (int i = 0; i < 16; i++) {
    int k = i * 64 + lane;
    #pragma unroll
    for (int b = 0; b < 8; b++) s[b] += w[i] * pl[b * 1024 + k];
  }
  #pragma unroll
  for (int m = 1; m <= 32; m <<= 1)
    #pragma unroll
    for (int b = 0; b < 8; b++) s[b] += __shfl_xor(s[b], m, 64);
  if (lane < 8) out[(size_t)lane * NOUT + o] = s[lane] + up_b[o];
}

extern "C" void kernel_launch(void* const* d_in, const int* in_sizes, int n_in,
                              void* d_out, int out_size, void* d_ws, size_t ws_size,
                              hipStream_t stream) {
  const float* images = (const float*)d_in[0];
  const float* masks  = (const float*)d_in[1];
  const float* feat   = (const float*)d_in[2];   // [B,1024(loc),1024(emb)]
  const float* coords = (const float*)d_in[3];
  const float* c1w  = (const float*)d_in[5];
  const float* c1b  = (const float*)d_in[6];
  const float* ln1w = (const float*)d_in[7];
  const float* ln1b = (const float*)d_in[8];
  const float* c2w  = (const float*)d_in[9];
  const float* c2b  = (const float*)d_in[10];
  const float* ln2w = (const float*)d_in[11];
  const float* ln2b = (const float*)d_in[12];
  const float* c3w  = (const float*)d_in[13];
  const float* c3b  = (const float*)d_in[14];
  const float* up_w = (const float*)d_in[15];
  const float* up_b = (const float*)d_in[16];
  float* out = (float*)d_out;

  char* ws = (char*)d_ws;
  size_t off = 0;
  auto alloc = [&](size_t bytes) -> void* {
    void* p = ws + off;
    off = (off + bytes + 255) & ~(size_t)255;
    return p;
  };
  float* Aw    = (float*)alloc(8192 * 4);
  float* cnt   = (float*)alloc(8 * 4);
  float* sumAw = (float*)alloc(8 * 4);
  size_t zeroBytes = off;
  int*   idxc  = (int*)alloc(MC * 4);
  float* Awc   = (float*)alloc(MC * 4);
  float* pa    = (float*)alloc(8192 * 4);
  float* pf    = (float*)alloc(8192 * 4);
  float* partials  = (float*)alloc((size_t)384 * 1024 * 4);   // [96*4][1024]
  float* partialsF = (float*)alloc((size_t)384 * 1024 * 4);
  float* zn   = (float*)alloc(8192 * 4);
  short* c1wb = (short*)alloc((size_t)CH1 * K1 * 2);
  short* w2p  = (short*)alloc((size_t)CH2 * CH2 * 2);
  short* A1g  = (short*)alloc((size_t)M1 * K1 * 2);      // full im2col (gather src)
  short* y1c  = (short*)alloc((size_t)M1C * 256 * 2);    // compacted conv1 out
  short* act1c = (short*)alloc((size_t)MC * 1024 * 2);   // compacted conv2 input
  short* y2c  = (short*)alloc((size_t)MC * 1024 * 2);    // compacted conv2 out

  int n4 = (int)(zeroBytes / 16);
  k_zero<<<(n4 + 255) / 256, 256, 0, stream>>>((float4*)d_ws, n4);
  k_wcast<<<4096, 256, 0, stream>>>(c1w, c2w, c1wb, w2p);
  k_pts<<<NB * 49, 256, 0, stream>>>(coords, Aw, cnt, sumAw);
  k_compact<<<NB, 256, 0, stream>>>(Aw, idxc, Awc);
  k_im2col<<<512, 256, 0, stream>>>(images, masks, A1g);
  k_gemm64<K1, 256, 1><<<dim3(M1C / 64, 4), 256, 0, stream>>>(A1g, idxc, c1wb, c1b, y1c);
  k_ln1c<<<M1C / 64, 256, 0, stream>>>(y1c, ln1w, ln1b, act1c);
  k_gemm64<1024, 1024, 0><<<dim3(MC / 64, 16), 256, 0, stream>>>(act1c, nullptr, w2p, c2b, y2c);
  k_poolboth<<<96, 256, 0, stream>>>(y2c, feat, idxc, ln2w, ln2b, Awc, partials, partialsF);
  k_red<<<32, 256, 0, stream>>>(partials, partialsF, pa, pf);
  k_mix<<<256, 256, 0, stream>>>(pa, pf, sumAw, cnt, c3w, c3b, zn);
  k_out<<<NOUT / 4, 256, 0, stream>>>(zn, up_w, up_b, out);
}

// Round 14
// 112.254 us; speedup vs baseline: 1.5022x; 1.0659x over previous
//
#include <hip/hip_runtime.h>
#include <stdint.h>

// Problem constants
#define NB 8
#define HIN 448
#define CH1 256
#define CH2 1024
#define NLOC 1024        // 32*32
#define M2 8192          // NB*NLOC
#define M1 32768         // NB*64*64 conv1 output locations
#define K1 224           // padded im2col K: c*56 + r*8 + cc(0..7), cc==7 -> 0
#define NPTS 12544
#define NOUT 4096
#define CAP 384          // per-batch compacted-row capacity (>= 18*18=324 bound)
#define MC (NB * CAP)    // 3072 compacted conv2 rows
#define M1C (MC * 4)     // 12288 compacted conv1 rows

typedef __attribute__((ext_vector_type(8))) short bf16x8;
typedef __attribute__((ext_vector_type(4))) float f32x4;

__device__ __forceinline__ short f2bf(float f) {
  uint32_t u = __builtin_bit_cast(uint32_t, f);
  uint32_t r = (u + 0x7fffu + ((u >> 16) & 1u)) >> 16;
  return (short)r;
}
__device__ __forceinline__ float bf2f(short s) {
  return __builtin_bit_cast(float, (uint32_t)(uint16_t)s << 16);
}
__device__ __forceinline__ float gelu_f(float x) {
  return 0.5f * x * (1.0f + erff(x * 0.70710678118654752f));
}
__device__ __forceinline__ void gload_lds16(const void* g, void* l) {
  __builtin_amdgcn_global_load_lds((const __attribute__((address_space(1))) unsigned int*)g,
                                   (__attribute__((address_space(3))) unsigned int*)l, 16, 0, 0);
}

// ---- merged: workspace zero + weight cast/permute (independent jobs) ----
__global__ void k_prep(const float* __restrict__ c1w, const float* __restrict__ c2w,
                       short* __restrict__ c1wb, short* __restrict__ w2p,
                       float4* __restrict__ zp, int n4) {
  int i = blockIdx.x * 256 + threadIdx.x;
  if (i < n4) zp[i] = make_float4(0.f, 0.f, 0.f, 0.f);
  if (i < CH1 * K1) {
    int o = i / K1, k = i - o * K1;
    int c = k / 56, kk = k - c * 56, r = kk >> 3, cc = kk & 7;
    c1wb[i] = f2bf(cc < 7 ? c1w[((o * 4 + c) * 7 + r) * 7 + cc] : 0.0f);
  }
  if (i < CH2 * CH2) {
    int o = i >> 10, k = i & 1023;
    int pos = k >> 8, ci = k & 255;
    w2p[i] = f2bf(c2w[(size_t)(o * 256 + ci) * 4 + pos]);
  }
}

// ---- point -> bilinear weight accumulation (LDS-aggregated, G12) ----
__global__ __launch_bounds__(256) void k_pts(const float* __restrict__ coords,
                                             float* __restrict__ Aw,
                                             float* __restrict__ cnt,
                                             float* __restrict__ sumAw) {
  __shared__ float lAw[NLOC];
  __shared__ int lcnt;
  __shared__ float wsum[4];
  int t = threadIdx.x;
  int b = blockIdx.x / 49;
  int blk = blockIdx.x - b * 49;
  for (int i = t; i < NLOC; i += 256) lAw[i] = 0.f;
  if (t == 0) lcnt = 0;
  __syncthreads();
  int pi = blk * 256 + t;
  float x = coords[((size_t)b * NPTS + pi) * 2];
  float y = coords[((size_t)b * NPTS + pi) * 2 + 1];
  bool valid = (x >= 0.0f);
  if (valid) {
    float gx = x * 32.0f - 0.5f, gy = y * 32.0f - 0.5f;
    float x0f = floorf(gx), y0f = floorf(gy);
    int x0 = (int)x0f, y0 = (int)y0f;
    float wx1 = gx - x0f, wx0 = 1.0f - wx1;
    float wy1 = gy - y0f, wy0 = 1.0f - wy1;
    int xs[2] = {x0, x0 + 1}, ys[2] = {y0, y0 + 1};
    float wxs[2] = {wx0, wx1}, wys[2] = {wy0, wy1};
    #pragma unroll
    for (int cy = 0; cy < 2; cy++)
      #pragma unroll
      for (int cx = 0; cx < 2; cx++) {
        int ix = xs[cx], iy = ys[cy];
        if (ix >= 0 && ix < 32 && iy >= 0 && iy < 32)
          atomicAdd(&lAw[iy * 32 + ix], wxs[cx] * wys[cy]);
      }
  }
  unsigned long long ball = __ballot(valid);
  if ((t & 63) == 0) atomicAdd(&lcnt, (int)__popcll(ball));
  __syncthreads();
  float tsum = 0.f;
  for (int i = t; i < NLOC; i += 256) {
    float v = lAw[i];
    tsum += v;
    if (v != 0.f) atomicAdd(&Aw[b * NLOC + i], v);
  }
  #pragma unroll
  for (int m = 1; m <= 32; m <<= 1) tsum += __shfl_xor(tsum, m, 64);
  if ((t & 63) == 0) wsum[t >> 6] = tsum;
  __syncthreads();
  if (t == 0) {
    float bs = wsum[0] + wsum[1] + wsum[2] + wsum[3];
    if (bs != 0.f) atomicAdd(&sumAw[b], bs);
    if (lcnt) atomicAdd(&cnt[b], (float)lcnt);
  }
}

// ---- merged: compaction (blocks 0..7) + im2col (blocks 8..519) ----
__global__ __launch_bounds__(256) void k_cim(const float* __restrict__ Aw,
                                             int* __restrict__ idxc,
                                             float* __restrict__ Awc,
                                             const float* __restrict__ images,
                                             const float* __restrict__ masks,
                                             short* __restrict__ A1g) {
  __shared__ float S[28 * 452];
  int t = threadIdx.x;
  if (blockIdx.x < NB) {
    // ---- per-batch ordered prefix-scan compaction ----
    int* cnts = (int*)S;
    int* offs = cnts + 256;
    int b = blockIdx.x;
    int base = b * 1024 + t * 4;
    float w[4];
    int c = 0;
    #pragma unroll
    for (int j = 0; j < 4; j++) { w[j] = Aw[base + j]; c += (w[j] != 0.f) ? 1 : 0; }
    cnts[t] = c;
    offs[t] = c;
    __syncthreads();
    for (int s = 1; s < 256; s <<= 1) {
      int v = (t >= s) ? offs[t - s] : 0;
      __syncthreads();
      offs[t] += v;
      __syncthreads();
    }
    int pos = b * CAP + offs[t] - cnts[t];
    int lim = (b + 1) * CAP;
    #pragma unroll
    for (int j = 0; j < 4; j++)
      if (w[j] != 0.f && pos < lim) { idxc[pos] = base + j; Awc[pos] = w[j]; pos++; }
    int total = offs[255];
    for (int i = total + t; i < CAP; i += 256) {
      idxc[b * CAP + i] = b * 1024;
      Awc[b * CAP + i] = 0.f;
    }
    return;
  }
  // ---- im2col for conv1 (7x7 s7, zero duplication) ----
  int bid = blockIdx.x - NB;
  int b = bid >> 6, y = bid & 63;
  int y7 = y * 7;
  for (int p = t; p < 3136; p += 256) {
    int row = p / 112, c4 = p - row * 112;
    int c = row / 7, r = row - c * 7;
    const float* src = (c < 3)
        ? &images[((size_t)(b * 3 + c) * 448 + y7 + r) * 448 + c4 * 4]
        : &masks[((size_t)b * 448 + y7 + r) * 448 + c4 * 4];
    *(float4*)&S[row * 452 + c4 * 4] = *(const float4*)src;
  }
  __syncthreads();
  size_t obase = (size_t)bid * 64 * K1;
  #pragma unroll
  for (int it = 0; it < 7; it++) {
    int p = it * 256 + t;
    int x = p / 28, k16 = p - x * 28;
    const float* s = &S[k16 * 452 + x * 7];
    short o[8];
    #pragma unroll
    for (int j = 0; j < 7; j++) o[j] = f2bf(s[j]);
    o[7] = 0;
    *(bf16x8*)&A1g[obase + (size_t)p * 8] = *(bf16x8*)o;
  }
}

// ---- 64x64-tile bf16 BT GEMM (conv1c, gathered A rows) ----
template<int KDIM, int LDC, int MODE>
__global__ __launch_bounds__(256) void k_gemm64(
    const short* __restrict__ Amat, const int* __restrict__ idxc,
    const short* __restrict__ Bmat, const float* __restrict__ bias,
    short* __restrict__ Cout) {
  __shared__ __align__(16) char Lraw[16384];
  int t = threadIdx.x, lane = t & 63, wv = t >> 6;
  int mt0 = blockIdx.x * 64;
  int nt0 = blockIdx.y * 64;
  f32x4 acc[2][2];
  #pragma unroll
  for (int i = 0; i < 2; i++)
    #pragma unroll
    for (int j = 0; j < 2; j++) acc[i][j] = (f32x4){0.f, 0.f, 0.f, 0.f};

  int srow = lane >> 2, scol = (lane & 3) * 8;
  int wm = wv >> 1, wn = wv & 1;
  int l15 = lane & 15, lg = lane >> 4;

  int arow = mt0 + wv * 16 + srow;
  const short* Ap;
  if (MODE == 1) {
    int i = arow >> 2, pos = arow & 3;
    int loc = idxc[i];
    int b = loc >> 10, oy = (loc >> 5) & 31, ox = loc & 31;
    int yy = oy * 2 + (pos >> 1), xx = ox * 2 + (pos & 1);
    Ap = Amat + (size_t)((b * 64 + yy) * 64 + xx) * KDIM;
  } else {
    Ap = Amat + (size_t)arow * KDIM;
  }
  const short* Bp = Bmat + (size_t)(nt0 + wv * 16 + srow) * KDIM;

  auto STAGE = [&](int buf, int kt) {
    int k0 = kt * 32;
    char* As = Lraw + buf * 8192;
    char* Bs = As + 4096;
    gload_lds16(Ap + k0 + scol, As + wv * 1024);
    gload_lds16(Bp + k0 + scol, Bs + wv * 1024);
  };

  const int NT = KDIM / 32;
  STAGE(0, 0);
  __syncthreads();
  int cur = 0;
  #pragma unroll 2
  for (int kt = 0; kt < NT; kt++) {
    if (kt + 1 < NT) STAGE(cur ^ 1, kt + 1);
    const short* As = (const short*)(Lraw + cur * 8192);
    const short* Bs = As + 2048;
    bf16x8 af[2], bfr[2];
    #pragma unroll
    for (int i = 0; i < 2; i++)
      af[i] = *(const bf16x8*)&As[(wm * 32 + i * 16 + l15) * 32 + lg * 8];
    #pragma unroll
    for (int j = 0; j < 2; j++)
      bfr[j] = *(const bf16x8*)&Bs[(wn * 32 + j * 16 + l15) * 32 + lg * 8];
    #pragma unroll
    for (int i = 0; i < 2; i++)
      #pragma unroll
      for (int j = 0; j < 2; j++)
        acc[i][j] = __builtin_amdgcn_mfma_f32_16x16x32_bf16(af[i], bfr[j], acc[i][j], 0, 0, 0);
    __syncthreads();
    cur ^= 1;
  }

  short* ct = (short*)Lraw;
  #pragma unroll
  for (int i = 0; i < 2; i++)
    #pragma unroll
    for (int j = 0; j < 2; j++) {
      int cl = wn * 32 + j * 16 + l15;
      float bv = bias[nt0 + cl];
      #pragma unroll
      for (int reg = 0; reg < 4; reg++) {
        int rl = wm * 32 + i * 16 + lg * 4 + reg;
        ct[rl * 68 + cl] = f2bf(acc[i][j][reg] + bv);
      }
    }
  __syncthreads();
  #pragma unroll
  for (int it = 0; it < 2; it++) {
    int p = it * 256 + t;
    int row = p >> 3, cc = (p & 7) * 8;
    bf16x8 v = *(const bf16x8*)&ct[row * 68 + cc];
    *(bf16x8*)&Cout[(size_t)(mt0 + row) * LDC + nt0 + cc] = v;
  }
}

// ---- 128x64-tile bf16 BT GEMM (conv2c; proven R6/R7 structure) ----
template<int KDIM>
__global__ __launch_bounds__(256) void k_gemm(
    const short* __restrict__ Amat, const short* __restrict__ Bmat,
    const float* __restrict__ bias, short* __restrict__ Cout, int ldc) {
  __shared__ __align__(16) char Lraw[24576];
  int t = threadIdx.x, lane = t & 63, wv = t >> 6;
  int mt0 = blockIdx.x * 128;
  int nt0 = blockIdx.y * 64;
  f32x4 acc[4][2];
  #pragma unroll
  for (int i = 0; i < 4; i++)
    #pragma unroll
    for (int j = 0; j < 2; j++) acc[i][j] = (f32x4){0.f, 0.f, 0.f, 0.f};

  int srow = lane >> 2, scol = (lane & 3) * 8;
  int wm = wv >> 1, wn = wv & 1;
  int l15 = lane & 15, lg = lane >> 4;
  int r0 = wv * 16, r1 = 64 + wv * 16;

  auto STAGE = [&](int buf, int kt) {
    int k0 = kt * 32;
    char* As = Lraw + buf * 12288;
    char* Bs = As + 8192;
    gload_lds16(&Amat[(size_t)(mt0 + r0 + srow) * KDIM + k0 + scol], As + r0 * 64);
    gload_lds16(&Amat[(size_t)(mt0 + r1 + srow) * KDIM + k0 + scol], As + r1 * 64);
    gload_lds16(&Bmat[(size_t)(nt0 + r0 + srow) * KDIM + k0 + scol], Bs + r0 * 64);
  };

  const int NT = KDIM / 32;
  STAGE(0, 0);
  __syncthreads();
  int cur = 0;
  #pragma unroll 2
  for (int kt = 0; kt < NT; kt++) {
    if (kt + 1 < NT) STAGE(cur ^ 1, kt + 1);
    const short* As = (const short*)(Lraw + cur * 12288);
    const short* Bs = As + 4096;
    bf16x8 af[4], bfr[2];
    #pragma unroll
    for (int i = 0; i < 4; i++)
      af[i] = *(const bf16x8*)&As[(wm * 64 + i * 16 + l15) * 32 + lg * 8];
    #pragma unroll
    for (int j = 0; j < 2; j++)
      bfr[j] = *(const bf16x8*)&Bs[(wn * 32 + j * 16 + l15) * 32 + lg * 8];
    #pragma unroll
    for (int i = 0; i < 4; i++)
      #pragma unroll
      for (int j = 0; j < 2; j++)
        acc[i][j] = __builtin_amdgcn_mfma_f32_16x16x32_bf16(af[i], bfr[j], acc[i][j], 0, 0, 0);
    __syncthreads();
    cur ^= 1;
  }

  short* ct = (short*)Lraw;
  #pragma unroll
  for (int i = 0; i < 4; i++)
    #pragma unroll
    for (int j = 0; j < 2; j++) {
      int cl = wn * 32 + j * 16 + l15;
      float bv = bias[nt0 + cl];
      #pragma unroll
      for (int reg = 0; reg < 4; reg++) {
        int rl = wm * 64 + i * 16 + lg * 4 + reg;
        ct[rl * 68 + cl] = f2bf(acc[i][j][reg] + bv);
      }
    }
  __syncthreads();
  #pragma unroll
  for (int it = 0; it < 4; it++) {
    int p = it * 256 + t;
    int row = p >> 3, cc = (p & 7) * 8;
    bf16x8 v = *(const bf16x8*)&ct[row * 68 + cc];
    *(bf16x8*)&Cout[(size_t)(mt0 + row) * ldc + nt0 + cc] = v;
  }
}

// ---- LN(256)+GELU on compacted conv1 rows -> act1c[i][pos*256+ch] ----
__global__ __launch_bounds__(256) void k_ln1c(const short* __restrict__ y1c,
                                              const float* __restrict__ ln1w,
                                              const float* __restrict__ ln1b,
                                              short* __restrict__ act1c) {
  int t = threadIdx.x, wv = t >> 6, lane = t & 63;
  int c = lane * 4;
  float lw[4], lb[4];
  #pragma unroll
  for (int j = 0; j < 4; j++) { lw[j] = ln1w[c + j]; lb[j] = ln1b[c + j]; }
  int j0 = blockIdx.x * 64 + wv * 16;
  for (int r = 0; r < 16; r++) {
    int j = j0 + r;
    short4 v4 = *(const short4*)&y1c[(size_t)j * 256 + c];
    float xs[4] = {bf2f(v4.x), bf2f(v4.y), bf2f(v4.z), bf2f(v4.w)};
    float s = 0.f, q = 0.f;
    #pragma unroll
    for (int jj = 0; jj < 4; jj++) { s += xs[jj]; q += xs[jj] * xs[jj]; }
    #pragma unroll
    for (int mm = 1; mm <= 32; mm <<= 1) { s += __shfl_xor(s, mm, 64); q += __shfl_xor(q, mm, 64); }
    float u = s * (1.0f / 256.0f);
    float rs = rsqrtf(q * (1.0f / 256.0f) - u * u + 1e-6f);
    short o[4];
    #pragma unroll
    for (int jj = 0; jj < 4; jj++) o[jj] = f2bf(gelu_f(lw[jj] * ((xs[jj] - u) * rs) + lb[jj]));
    size_t addr = (size_t)(j >> 2) * 1024 + (size_t)(j & 3) * 256 + c;
    *(short4*)&act1c[addr] = make_short4(o[0], o[1], o[2], o[3]);
  }
}

// ---- merged LN(1024)+GELU+pool over y2c AND gathered-feat pool, atomic-free ----
__global__ __launch_bounds__(256) void k_poolboth(const short* __restrict__ y2c,
                                                  const float* __restrict__ feat,
                                                  const int* __restrict__ idxc,
                                                  const float* __restrict__ ln2w,
                                                  const float* __restrict__ ln2b,
                                                  const float* __restrict__ Awc,
                                                  float* __restrict__ partials,
                                                  float* __restrict__ partialsF) {
  int t = threadIdx.x, wv = t >> 6, lane = t & 63;
  int b = blockIdx.x / 12, chunk = blockIdx.x % 12;
  int base = b * CAP + chunk * 32;
  int c0 = lane * 16;
  float lw[16], lb[16], wacc[16], facc[16];
  #pragma unroll
  for (int j = 0; j < 16; j++) {
    lw[j] = ln2w[c0 + j];
    lb[j] = ln2b[c0 + j];
    wacc[j] = 0.f;
    facc[j] = 0.f;
  }
  for (int pass = 0; pass < 8; pass++) {
    int row = base + pass * 4 + wv;
    float wt = Awc[row];
    if (wt == 0.f) continue;
    const float4* fp = (const float4*)(feat + (size_t)idxc[row] * 1024 + c0);
    #pragma unroll
    for (int j = 0; j < 4; j++) {
      float4 v = fp[j];
      facc[j * 4 + 0] += wt * v.x;
      facc[j * 4 + 1] += wt * v.y;
      facc[j * 4 + 2] += wt * v.z;
      facc[j * 4 + 3] += wt * v.w;
    }
    bf16x8 v0 = *(const bf16x8*)&y2c[(size_t)row * 1024 + c0];
    bf16x8 v1 = *(const bf16x8*)&y2c[(size_t)row * 1024 + c0 + 8];
    float xs[16];
    #pragma unroll
    for (int j = 0; j < 8; j++) { xs[j] = bf2f(v0[j]); xs[8 + j] = bf2f(v1[j]); }
    float s = 0.f, q = 0.f;
    #pragma unroll
    for (int j = 0; j < 16; j++) { s += xs[j]; q += xs[j] * xs[j]; }
    #pragma unroll
    for (int m = 1; m <= 32; m <<= 1) { s += __shfl_xor(s, m, 64); q += __shfl_xor(q, m, 64); }
    float u = s * (1.0f / 1024.0f);
    float rs = rsqrtf(q * (1.0f / 1024.0f) - u * u + 1e-6f);
    #pragma unroll
    for (int j = 0; j < 16; j++)
      wacc[j] += wt * gelu_f(lw[j] * ((xs[j] - u) * rs) + lb[j]);
  }
  float* dst = &partials[((size_t)blockIdx.x * 4 + wv) * 1024 + c0];
  float* dstF = &partialsF[((size_t)blockIdx.x * 4 + wv) * 1024 + c0];
  #pragma unroll
  for (int j = 0; j < 4; j++) {
    *(f32x4*)&dst[j * 4] = (f32x4){wacc[j * 4], wacc[j * 4 + 1], wacc[j * 4 + 2], wacc[j * 4 + 3]};
    *(f32x4*)&dstF[j * 4] = (f32x4){facc[j * 4], facc[j * 4 + 1], facc[j * 4 + 2], facc[j * 4 + 3]};
  }
}

// ---- reduce both partial arrays: 48 slots per batch each ----
__global__ __launch_bounds__(256) void k_red(const float* __restrict__ partials,
                                             const float* __restrict__ partialsF,
                                             float* __restrict__ pa,
                                             float* __restrict__ pf) {
  int c = blockIdx.x * 256 + threadIdx.x;
  int b = c >> 10, ch = c & 1023;
  const float* p = partials + (size_t)(b * 48) * 1024 + ch;
  const float* pF = partialsF + (size_t)(b * 48) * 1024 + ch;
  float s = 0.f, sf = 0.f;
  #pragma unroll 8
  for (int j = 0; j < 48; j++) {
    s += p[(size_t)j * 1024];
    sf += pF[(size_t)j * 1024];
  }
  pa[c] = s;
  pf[c] = sf;
}

// ---- conv3 folded past the pool: wave-per-channel, c3w read once ----
__global__ __launch_bounds__(256) void k_mix(const float* __restrict__ pa,
                                             const float* __restrict__ pf,
                                             const float* __restrict__ sumAw,
                                             const float* __restrict__ cnt,
                                             const float* __restrict__ c3w,
                                             const float* __restrict__ c3b,
                                             float* __restrict__ zn) {
  __shared__ float pl[8192];
  int t = threadIdx.x;
  for (int idx = t; idx < 2048; idx += 256)
    ((float4*)pl)[idx] = ((const float4*)pa)[idx];
  __syncthreads();
  int wv = t >> 6, lane = t & 63;
  int c = blockIdx.x * 4 + wv;
  float w[16];
  #pragma unroll
  for (int i = 0; i < 16; i++) w[i] = c3w[(size_t)c * 1024 + i * 64 + lane];
  float s[8];
  #pragma unroll
  for (int b = 0; b < 8; b++) s[b] = 0.f;
  #pragma unroll
  for (int i = 0; i < 16; i++) {
    int k = i * 64 + lane;
    #pragma unroll
    for (int b = 0; b < 8; b++) s[b] += w[i] * pl[b * 1024 + k];
  }
  #pragma unroll
  for (int m = 1; m <= 32; m <<= 1)
    #pragma unroll
    for (int b = 0; b < 8; b++) s[b] += __shfl_xor(s[b], m, 64);
  if (lane < 8) {
    float cv = cnt[lane];
    float z = s[lane] + sumAw[lane] * c3b[c] + pf[lane * 1024 + c];
    zn[lane * 1024 + c] = cv > 0.f ? z / cv : 0.f;
  }
}

// ---- final GEMV: 1024 blocks, one wave per output row, 8 batches/wave ----
__global__ __launch_bounds__(256) void k_out(const float* __restrict__ zn,
                                             const float* __restrict__ up_w,
                                             const float* __restrict__ up_b,
                                             float* __restrict__ out) {
  __shared__ float pl[8192];
  int t = threadIdx.x;
  for (int idx = t; idx < 2048; idx += 256)
    ((float4*)pl)[idx] = ((const float4*)zn)[idx];
  __syncthreads();
  int wv = t >> 6, lane = t & 63;
  int o = blockIdx.x * 4 + wv;
  float w[16];
  #pragma unroll
  for (int i = 0; i < 16; i++) w[i] = up_w[(size_t)o * 1024 + i * 64 + lane];
  float s[8];
  #pragma unroll
  for (int b = 0; b < 8; b++) s[b] = 0.f;
  #pragma unroll
  for (int i = 0; i < 16; i++) {
    int k = i * 64 + lane;
    #pragma unroll
    for (int b = 0; b < 8; b++) s[b] += w[i] * pl[b * 1024 + k];
  }
  #pragma unroll
  for (int m = 1; m <= 32; m <<= 1)
    #pragma unroll
    for (int b = 0; b < 8; b++) s[b] += __shfl_xor(s[b], m, 64);
  if (lane < 8) out[(size_t)lane * NOUT + o] = s[lane] + up_b[o];
}

extern "C" void kernel_launch(void* const* d_in, const int* in_sizes, int n_in,
                              void* d_out, int out_size, void* d_ws, size_t ws_size,
                              hipStream_t stream) {
  const float* images = (const float*)d_in[0];
  const float* masks  = (const float*)d_in[1];
  const float* feat   = (const float*)d_in[2];
  const float* coords = (const float*)d_in[3];
  const float* c1w  = (const float*)d_in[5];
  const float* c1b  = (const float*)d_in[6];
  const float* ln1w = (const float*)d_in[7];
  const float* ln1b = (const float*)d_in[8];
  const float* c2w  = (const float*)d_in[9];
  const float* c2b  = (const float*)d_in[10];
  const float* ln2w = (const float*)d_in[11];
  const float* ln2b = (const float*)d_in[12];
  const float* c3w  = (const float*)d_in[13];
  const float* c3b  = (const float*)d_in[14];
  const float* up_w = (const float*)d_in[15];
  const float* up_b = (const float*)d_in[16];
  float* out = (float*)d_out;

  char* ws = (char*)d_ws;
  size_t off = 0;
  auto alloc = [&](size_t bytes) -> void* {
    void* p = ws + off;
    off = (off + bytes + 255) & ~(size_t)255;
    return p;
  };
  float* Aw    = (float*)alloc(8192 * 4);
  float* cnt   = (float*)alloc(8 * 4);
  float* sumAw = (float*)alloc(8 * 4);
  size_t zeroBytes = off;
  int*   idxc  = (int*)alloc(MC * 4);
  float* Awc   = (float*)alloc(MC * 4);
  float* pa    = (float*)alloc(8192 * 4);
  float* pf    = (float*)alloc(8192 * 4);
  float* partials  = (float*)alloc((size_t)384 * 1024 * 4);
  float* partialsF = (float*)alloc((size_t)384 * 1024 * 4);
  float* zn   = (float*)alloc(8192 * 4);
  short* c1wb = (short*)alloc((size_t)CH1 * K1 * 2);
  short* w2p  = (short*)alloc((size_t)CH2 * CH2 * 2);
  short* A1g  = (short*)alloc((size_t)M1 * K1 * 2);
  short* y1c  = (short*)alloc((size_t)M1C * 256 * 2);
  short* act1c = (short*)alloc((size_t)MC * 1024 * 2);
  short* y2c  = (short*)alloc((size_t)MC * 1024 * 2);

  int n4 = (int)(zeroBytes / 16);
  k_prep<<<4096, 256, 0, stream>>>(c1w, c2w, c1wb, w2p, (float4*)d_ws, n4);
  k_pts<<<NB * 49, 256, 0, stream>>>(coords, Aw, cnt, sumAw);
  k_cim<<<NB + 512, 256, 0, stream>>>(Aw, idxc, Awc, images, masks, A1g);
  k_gemm64<K1, 256, 1><<<dim3(M1C / 64, 4), 256, 0, stream>>>(A1g, idxc, c1wb, c1b, y1c);
  k_ln1c<<<M1C / 64, 256, 0, stream>>>(y1c, ln1w, ln1b, act1c);
  k_gemm<1024><<<dim3(MC / 128, 16), 256, 0, stream>>>(act1c, w2p, c2b, y2c, 1024);
  k_poolboth<<<96, 256, 0, stream>>>(y2c, feat, idxc, ln2w, ln2b, Awc, partials, partialsF);
  k_red<<<32, 256, 0, stream>>>(partials, partialsF, pa, pf);
  k_mix<<<256, 256, 0, stream>>>(pa, pf, sumAw, cnt, c3w, c3b, zn);
  k_out<<<NOUT / 4, 256, 0, stream>>>(zn, up_w, up_b, out);
}